// Round 6
// baseline (899.244 us; speedup 1.0000x reference)
//
#include <hip/hip_runtime.h>
#include <hip/hip_fp16.h>
#include <float.h>

// ---- fixed problem shape ----
constexpr int NB  = 16;     // batch (clouds)
constexpr int NPT = 2048;   // points per cloud
constexpr int KK  = 20;     // kNN
constexpr int NEDGE = NB * NPT * KK;       // 655360
constexpr int C1 = 64, C2 = 128, EMB = 1024, OUT = 7;
constexpr int NNODE = NB * NPT;            // 32768
constexpr int E2_BLOCKS = 512;             // edge2 grid (2 blocks/CU, LDS-limited)
constexpr int N_E2_PART = 4096;            // edge2 stat partials (512 blocks x 8 row-groups)
constexpr int GRAM_GRID = 128;
constexpr int GRAM_ELEMS = C2 * C2 + C2;   // 16512 (Gram + colsum)
__device__ constexpr double R1d = (double)NEDGE;       // BN1/BN2 row count
__device__ constexpr double R3d = (double)(NB * NPT);  // BN3 row count
constexpr unsigned long long INF64 = ~0ull;

// ---------------- kNN: one wave per query, keys fully register-resident ----------------
// key[] must be indexed ONLY by compile-time constants (full unroll) or the
// array lands in scratch (round-4 profile: 525 MB spill writes, 278 us).
__global__ __launch_bounds__(256) void knn_kernel(const float* __restrict__ pos, unsigned short* __restrict__ idxo) {
  int t = threadIdx.x;
  int lane = t & 63, w = t >> 6;
  int bn = blockIdx.x * 4 + w;            // 8192 blocks x 4 waves = 32768 queries
  int b = bn >> 11, n = bn & (NPT - 1);
  const float* pb = pos + (size_t)b * NPT * 3;
  float xn = pb[n * 3], yn = pb[n * 3 + 1], zn = pb[n * 3 + 2];
  float sqn = xn * xn + yn * yn + zn * zn;

  unsigned long long key[32];
  #pragma unroll
  for (int i = 0; i < 32; ++i) {
    int m = i * 64 + lane;
    float xm = pb[m * 3], ym = pb[m * 3 + 1], zm = pb[m * 3 + 2];
    float sqm = xm * xm + ym * ym + zm * zm;
    float dt = xn * xm + yn * ym + zn * zm;
    float d = sqn + sqm - 2.0f * dt;
    unsigned ub = __float_as_uint(d);
    ub = (ub & 0x80000000u) ? ~ub : (ub | 0x80000000u);  // order-preserving map
    key[i] = ((unsigned long long)ub << 32) | (unsigned long long)(unsigned)m;
  }

  unsigned long long T = 0;
  int myidx = 0;
  for (int r = 0; r < KK; ++r) {
    unsigned long long t0[16];
    #pragma unroll
    for (int i = 0; i < 16; ++i) {
      unsigned long long a = key[2 * i]     >= T ? key[2 * i]     : INF64;
      unsigned long long c = key[2 * i + 1] >= T ? key[2 * i + 1] : INF64;
      t0[i] = a < c ? a : c;
    }
    #pragma unroll
    for (int s = 8; s > 0; s >>= 1)
      #pragma unroll
      for (int i = 0; i < 8; ++i)
        if (i < s) t0[i] = t0[i] < t0[i + s] ? t0[i] : t0[i + s];
    unsigned long long best = t0[0];
    #pragma unroll
    for (int off = 32; off > 0; off >>= 1) {
      unsigned long long o = (unsigned long long)__shfl_xor((long long)best, off, 64);
      best = best < o ? best : o;
    }
    if (lane == r) myidx = (int)(unsigned)(best & 0xffffffffull);
    T = best + 1;
  }
  if (lane < KK) idxo[(size_t)bn * KK + lane] = (unsigned short)myidx;
}

// ---------------- edge-feature first/second moments (6 + 21 doubles) ----------------
__global__ __launch_bounds__(256) void statse_kernel(const float* __restrict__ pos, const unsigned short* __restrict__ idx,
                                                     double* __restrict__ dstats) {
  float acc[27];
  #pragma unroll
  for (int i = 0; i < 27; ++i) acc[i] = 0.f;
  int t = threadIdx.x;
  for (int e = blockIdx.x * 256 + t; e < NEDGE; e += gridDim.x * 256) {
    int bn = e / KK;
    int b = bn >> 11, n = bn & (NPT - 1);
    int j = idx[e];
    const float* pb = pos + (size_t)b * NPT * 3;
    float f[6];
    f[0] = pb[n * 3]; f[1] = pb[n * 3 + 1]; f[2] = pb[n * 3 + 2];
    f[3] = pb[j * 3] - f[0]; f[4] = pb[j * 3 + 1] - f[1]; f[5] = pb[j * 3 + 2] - f[2];
    int p = 6;
    #pragma unroll
    for (int d = 0; d < 6; ++d) acc[d] += f[d];
    #pragma unroll
    for (int d = 0; d < 6; ++d)
      #pragma unroll
      for (int q = d; q < 6; ++q) { acc[p] += f[d] * f[q]; ++p; }
  }
  __shared__ float sred[4][27];
  int lane = t & 63, w = t >> 6;
  #pragma unroll
  for (int c = 0; c < 27; ++c) {
    float v = acc[c];
    #pragma unroll
    for (int off = 32; off > 0; off >>= 1) v += __shfl_down(v, off);
    if (lane == 0) sred[w][c] = v;
  }
  __syncthreads();
  if (t < 27) {
    double s = (double)sred[0][t] + (double)sred[1][t] + (double)sred[2][t] + (double)sred[3][t];
    atomicAdd(&dstats[t], s);
  }
}

// ---------------- BN1 coeffs from moments ----------------
__global__ void finalize1_kernel(const double* __restrict__ dstats, const float* __restrict__ W1,
                                 const float* __restrict__ b1, const float* __restrict__ g1,
                                 const float* __restrict__ be1, float* __restrict__ scale1,
                                 float* __restrict__ shift1) {
  int c = threadIdx.x;  // 64
  double m1[6], M2[6][6];
  for (int d = 0; d < 6; ++d) m1[d] = dstats[d];
  int p = 6;
  for (int d = 0; d < 6; ++d)
    for (int q = d; q < 6; ++q) { M2[d][q] = dstats[p]; M2[q][d] = dstats[p]; ++p; }
  double w[6];
  for (int d = 0; d < 6; ++d) w[d] = W1[d * C1 + c];
  double wm = 0, quad = 0;
  for (int d = 0; d < 6; ++d) wm += w[d] * m1[d];
  for (int d = 0; d < 6; ++d) {
    double s = 0;
    for (int q = 0; q < 6; ++q) s += M2[d][q] * w[q];
    quad += w[d] * s;
  }
  double bb = b1[c];
  double mean = wm / R1d + bb;
  double E2 = (quad + 2.0 * bb * wm) / R1d + bb * bb;
  double var = E2 - mean * mean;
  double sc = (double)g1[c] / sqrt(var + 1e-5);
  scale1[c] = (float)sc;
  shift1[c] = (float)((double)be1[c] - mean * sc);
}

// ---------------- fused edge pass v2: 8-node (160-edge) tiles ----------------
// W2 in LDS once per block; acc[20][4] register accumulators per thread
// (thread = row-group rg (node) x channel-quad cq); per-node max/min entirely
// thread-local -> no reductions, 2 barriers per 8 nodes.
__global__ __launch_bounds__(256) void edge2_kernel(const float* __restrict__ pos, const unsigned short* __restrict__ idx,
    const float* __restrict__ W1, const float* __restrict__ b1,
    const float* __restrict__ scale1, const float* __restrict__ shift1,
    const float* __restrict__ W2, const float* __restrict__ b2,
    __half2* __restrict__ am, double* __restrict__ part) {
  constexpr int TROWS = 160;            // 8 nodes x 20 edges
  __shared__ float w2s[C1 * C2];        // 32 KiB
  __shared__ float hs[TROWS * C1];      // 40 KiB
  __shared__ float es[TROWS * 6];       // 3.75 KiB
  int t = threadIdx.x;

  // stage W2 (row-major [64][128]) once per block
  {
    float4* d = (float4*)w2s; const float4* s = (const float4*)W2;
    #pragma unroll
    for (int q = 0; q < 8; ++q) d[t + 256 * q] = s[t + 256 * q];
  }
  // per-thread W1 column (c = t&63) + BN1 params (registers, loaded once)
  int c1col = t & 63;
  float w1c[6];
  #pragma unroll
  for (int d = 0; d < 6; ++d) w1c[d] = W1[d * C1 + c1col];
  float b1c = b1[c1col], s1c = scale1[c1col], sh1c = shift1[c1col];
  // per-thread output ownership: node row-group rg, channel quad c0..c0+3
  int cq = t & 31, rg = t >> 5;
  int c0 = cq * 4;
  float4 b2q = *(const float4*)&b2[c0];
  double accs[4] = {0, 0, 0, 0}, accq[4] = {0, 0, 0, 0};

  for (int tile = blockIdx.x; tile < NNODE / 8; tile += E2_BLOCKS) {
    // P1: gather 160 edges x 6 comps
    for (int i = t; i < TROWS * 6; i += 256) {
      int r = i / 6, comp = i - r * 6;
      int e = tile * TROWS + r;
      int bn = e / KK;
      int b = bn >> 11, n = bn & (NPT - 1);
      int j = idx[e];
      const float* pb = pos + (size_t)b * NPT * 3;
      float v;
      if (comp < 3) v = pb[n * 3 + comp];
      else          v = pb[j * 3 + comp - 3] - pb[n * 3 + comp - 3];
      es[i] = v;
    }
    __syncthreads();
    // P2: h = relu(bn1(e @ W1))  (160 x 64)
    #pragma unroll
    for (int i = 0; i < (TROWS * C1) / 256; ++i) {  // 40
      int slot = t + 256 * i;
      int r = slot >> 6;
      float a = b1c;
      #pragma unroll
      for (int d = 0; d < 6; ++d) a += es[r * 6 + d] * w1c[d];
      a = a * s1c + sh1c;
      hs[slot] = a > 0.f ? a : 0.f;
    }
    __syncthreads();
    // P3: a2 = h @ W2 for my 20 rows x 4 channels (register-blocked)
    float acc[20][4];
    #pragma unroll
    for (int r = 0; r < 20; ++r) {
      acc[r][0] = 0.f; acc[r][1] = 0.f; acc[r][2] = 0.f; acc[r][3] = 0.f;
    }
    int hbase = rg * 20 * C1;
    #pragma unroll 2
    for (int j = 0; j < C1; j += 4) {
      float4 wq0 = *(const float4*)&w2s[(j + 0) * C2 + c0];
      float4 wq1 = *(const float4*)&w2s[(j + 1) * C2 + c0];
      float4 wq2 = *(const float4*)&w2s[(j + 2) * C2 + c0];
      float4 wq3 = *(const float4*)&w2s[(j + 3) * C2 + c0];
      #pragma unroll
      for (int r = 0; r < 20; ++r) {
        float4 hv = *(const float4*)&hs[hbase + r * C1 + j];
        acc[r][0] += hv.x * wq0.x + hv.y * wq1.x + hv.z * wq2.x + hv.w * wq3.x;
        acc[r][1] += hv.x * wq0.y + hv.y * wq1.y + hv.z * wq2.y + hv.w * wq3.y;
        acc[r][2] += hv.x * wq0.z + hv.y * wq1.z + hv.z * wq2.z + hv.w * wq3.z;
        acc[r][3] += hv.x * wq0.w + hv.y * wq1.w + hv.z * wq2.w + hv.w * wq3.w;
      }
    }
    // epilogue: bias, per-tile f32 stats, thread-local node max/min
    float sm[4] = {0, 0, 0, 0}, sq[4] = {0, 0, 0, 0};
    float mx[4] = {-FLT_MAX, -FLT_MAX, -FLT_MAX, -FLT_MAX};
    float mn[4] = {FLT_MAX, FLT_MAX, FLT_MAX, FLT_MAX};
    #pragma unroll
    for (int r = 0; r < 20; ++r) {
      float a0 = acc[r][0] + b2q.x;
      float a1 = acc[r][1] + b2q.y;
      float a2 = acc[r][2] + b2q.z;
      float a3 = acc[r][3] + b2q.w;
      sm[0] += a0; sq[0] += a0 * a0; mx[0] = fmaxf(mx[0], a0); mn[0] = fminf(mn[0], a0);
      sm[1] += a1; sq[1] += a1 * a1; mx[1] = fmaxf(mx[1], a1); mn[1] = fminf(mn[1], a1);
      sm[2] += a2; sq[2] += a2 * a2; mx[2] = fmaxf(mx[2], a2); mn[2] = fminf(mn[2], a2);
      sm[3] += a3; sq[3] += a3 * a3; mx[3] = fmaxf(mx[3], a3); mn[3] = fminf(mn[3], a3);
    }
    #pragma unroll
    for (int k = 0; k < 4; ++k) { accs[k] += (double)sm[k]; accq[k] += (double)sq[k]; }
    int node = tile * 8 + rg;
    __half2* dst = &am[(size_t)node * C2 + c0];
    dst[0] = __floats2half2_rn(mx[0], mn[0]);
    dst[1] = __floats2half2_rn(mx[1], mn[1]);
    dst[2] = __floats2half2_rn(mx[2], mn[2]);
    dst[3] = __floats2half2_rn(mx[3], mn[3]);
    __syncthreads();  // protect hs/es before next tile's writes
  }
  // write per-(block,rg) f64 partials: layout part[(blk*8+rg)*256 + {c | 128+c}]
  #pragma unroll
  for (int k = 0; k < 4; ++k) {
    part[((size_t)blockIdx.x * 8 + rg) * 256 + c0 + k] = accs[k];
    part[((size_t)blockIdx.x * 8 + rg) * 256 + 128 + c0 + k] = accq[k];
  }
}

// ---------------- BN2 finalize: reduce partials, one block per channel ----------------
__global__ __launch_bounds__(256) void finalize2_kernel(const double* __restrict__ part,
                                 const float* __restrict__ g2w, const float* __restrict__ be2,
                                 float* __restrict__ scale2, float* __restrict__ shift2) {
  int c = blockIdx.x;   // 128
  int t = threadIdx.x;  // 256
  double s = 0, q = 0;
  for (int i = t; i < N_E2_PART; i += 256) {
    s += part[(size_t)i * 256 + c];
    q += part[(size_t)i * 256 + 128 + c];
  }
  __shared__ double shs[256], shq[256];
  shs[t] = s; shq[t] = q; __syncthreads();
  for (int off = 128; off > 0; off >>= 1) {
    if (t < off) { shs[t] += shs[t + off]; shq[t] += shq[t + off]; }
    __syncthreads();
  }
  if (t == 0) {
    double mean = shs[0] / R1d;
    double var = shq[0] / R1d - mean * mean;
    double sc = (double)g2w[c] / sqrt(var + 1e-5);
    scale2[c] = (float)sc;
    shift2[c] = (float)((double)be2[c] - mean * sc);
  }
}

// node value on the fly: relu(scale * (scale>=0 ? max : min) + shift)
static __device__ __forceinline__ float node_val(__half2 h2, float s, float sh) {
  float A = __low2float(h2), N = __high2float(h2);
  float v = (s >= 0.f ? A : N) * s + sh;
  return v > 0.f ? v : 0.f;
}

// ---------------- Gram partials: BN2 applied on the fly; private 128x128 partial + colsum ----------------
__global__ __launch_bounds__(256) void gram_part_kernel(const __half2* __restrict__ am,
                                                        const float* __restrict__ scale2, const float* __restrict__ shift2,
                                                        float* __restrict__ part) {
  __shared__ float tile[64 * C2];  // 32 KiB
  __shared__ float s_s[C2], s_h[C2];
  int t = threadIdx.x;
  if (t < C2) { s_s[t] = scale2[t]; s_h[t] = shift2[t]; }
  __syncthreads();
  int i = t & 127, jh = t >> 7;
  float acc[64];
  #pragma unroll
  for (int u = 0; u < 64; ++u) acc[u] = 0.f;
  float csum = 0.f;
  for (int tl = blockIdx.x; tl < NNODE / 64; tl += GRAM_GRID) {
    const __half2* a2 = am + (size_t)tl * 64 * C2;
    #pragma unroll
    for (int q = 0; q < 32; ++q) {
      int e = q * 256 + t;
      int c = e & 127;
      tile[e] = node_val(a2[e], s_s[c], s_h[c]);
    }
    __syncthreads();
    #pragma unroll 4
    for (int r = 0; r < 64; ++r) {
      float xi = tile[r * C2 + i];
      const float4* row4 = (const float4*)&tile[r * C2 + jh * 64];
      #pragma unroll
      for (int u4 = 0; u4 < 16; ++u4) {
        float4 v = row4[u4];
        acc[u4 * 4 + 0] += xi * v.x;
        acc[u4 * 4 + 1] += xi * v.y;
        acc[u4 * 4 + 2] += xi * v.z;
        acc[u4 * 4 + 3] += xi * v.w;
      }
    }
    if (t < 128) {
      #pragma unroll 8
      for (int r = 0; r < 64; ++r) csum += tile[r * C2 + t];
    }
    __syncthreads();
  }
  float* pb = part + (size_t)blockIdx.x * GRAM_ELEMS;
  float4* pout = (float4*)(pb + (size_t)i * C2 + jh * 64);
  #pragma unroll
  for (int u4 = 0; u4 < 16; ++u4)
    pout[u4] = make_float4(acc[u4 * 4], acc[u4 * 4 + 1], acc[u4 * 4 + 2], acc[u4 * 4 + 3]);
  if (t < 128) pb[C2 * C2 + t] = csum;
}

// ---------------- Gram reduce: sum partials -> f64 G2 + nodesum ----------------
__global__ __launch_bounds__(256) void gram_reduce_kernel(const float* __restrict__ part,
                                                          double* __restrict__ G2, double* __restrict__ nodesum) {
  int e = blockIdx.x * 256 + threadIdx.x;
  if (e >= GRAM_ELEMS) return;
  double s = 0;
  for (int p = 0; p < GRAM_GRID; ++p) s += (double)part[(size_t)p * GRAM_ELEMS + e];
  if (e < C2 * C2) G2[e] = s;
  else nodesum[e - C2 * C2] = s;
}

// ---------------- BN3 coeffs from Gram ----------------
__global__ __launch_bounds__(128) void finalize3_kernel(const double* __restrict__ G2, const double* __restrict__ nodesum,
    const float* __restrict__ W3, const float* __restrict__ b3,
    const float* __restrict__ g3, const float* __restrict__ be3,
    float* __restrict__ scale3, float* __restrict__ shift3) {
  int c = blockIdx.x;   // 1024 channels
  int t = threadIdx.x;  // 128
  __shared__ double wsh[128];
  __shared__ double sh[128];
  double w = W3[(size_t)t * EMB + c];
  wsh[t] = w;
  __syncthreads();
  double rowdot = 0;
  for (int j = 0; j < 128; ++j) rowdot += G2[(size_t)j * C2 + t] * wsh[j];
  sh[t] = w * rowdot;
  __syncthreads();
  for (int off = 64; off > 0; off >>= 1) { if (t < off) sh[t] += sh[t + off]; __syncthreads(); }
  double quad = sh[0];
  __syncthreads();
  sh[t] = w * nodesum[t];
  __syncthreads();
  for (int off = 64; off > 0; off >>= 1) { if (t < off) sh[t] += sh[t + off]; __syncthreads(); }
  if (t == 0) {
    double wm = sh[0];
    double bb = b3[c];
    double mean = wm / R3d + bb;
    double E2 = (quad + 2.0 * bb * wm) / R3d + bb * bb;
    double var = E2 - mean * mean;
    double sc = (double)g3[c] / sqrt(var + 1e-5);
    scale3[c] = (float)sc;
    shift3[c] = (float)((double)be3[c] - mean * sc);
  }
}

// ---------------- linear1 apply (BN2 on the fly) + BN3 + ReLU -> per-row-tile partial max/sum ----------------
__global__ __launch_bounds__(256) void apply3pool_kernel(const __half2* __restrict__ am,
    const float* __restrict__ scale2, const float* __restrict__ shift2,
    const float* __restrict__ W3, const float* __restrict__ b3,
    const float* __restrict__ scale3, const float* __restrict__ shift3,
    float* __restrict__ pp, float* __restrict__ ps) {
  __shared__ float tile[32 * C2];  // 16 KiB
  __shared__ float s_s[C2], s_h[C2];
  int rt = blockIdx.x;  // 1024 row tiles of 32 rows
  int ct = blockIdx.y;  // 2 column halves
  int t = threadIdx.x;
  if (t < C2) { s_s[t] = scale2[t]; s_h[t] = shift2[t]; }
  __syncthreads();
  int c0 = ct * 512 + t;
  int c1 = c0 + 256;
  const __half2* a2 = am + (size_t)rt * 32 * C2;
  #pragma unroll
  for (int q = 0; q < 16; ++q) {
    int e = q * 256 + t;
    int c = e & 127;
    tile[e] = node_val(a2[e], s_s[c], s_h[c]);
  }
  __syncthreads();
  float a0[32], a1[32];
  #pragma unroll
  for (int r = 0; r < 32; ++r) { a0[r] = 0.f; a1[r] = 0.f; }
  for (int j = 0; j < 128; j += 4) {
    float w00 = W3[(size_t)j * EMB + c0], w01 = W3[(size_t)(j + 1) * EMB + c0];
    float w02 = W3[(size_t)(j + 2) * EMB + c0], w03 = W3[(size_t)(j + 3) * EMB + c0];
    float w10 = W3[(size_t)j * EMB + c1], w11 = W3[(size_t)(j + 1) * EMB + c1];
    float w12 = W3[(size_t)(j + 2) * EMB + c1], w13 = W3[(size_t)(j + 3) * EMB + c1];
    #pragma unroll
    for (int r = 0; r < 32; ++r) {
      float4 v = *(const float4*)&tile[r * C2 + j];
      a0[r] += v.x * w00 + v.y * w01 + v.z * w02 + v.w * w03;
      a1[r] += v.x * w10 + v.y * w11 + v.z * w12 + v.w * w13;
    }
  }
  float b30 = b3[c0], s30 = scale3[c0], sh30 = shift3[c0];
  float b31 = b3[c1], s31 = scale3[c1], sh31 = shift3[c1];
  float mx0 = 0.f, sm0 = 0.f, mx1 = 0.f, sm1 = 0.f;
  #pragma unroll
  for (int r = 0; r < 32; ++r) {
    float x0 = (a0[r] + b30) * s30 + sh30; x0 = x0 > 0.f ? x0 : 0.f; mx0 = mx0 > x0 ? mx0 : x0; sm0 += x0;
    float x1 = (a1[r] + b31) * s31 + sh31; x1 = x1 > 0.f ? x1 : 0.f; mx1 = mx1 > x1 ? mx1 : x1; sm1 += x1;
  }
  float* ppb = pp + (size_t)rt * EMB;
  float* psb = ps + (size_t)rt * EMB;
  ppb[c0] = mx0; psb[c0] = sm0;
  ppb[c1] = mx1; psb[c1] = sm1;
}

// ---------------- pool reduce: per (b,c) max/sum over 64 row tiles ----------------
__global__ __launch_bounds__(256) void poolreduce_kernel(const float* __restrict__ pp, const float* __restrict__ ps,
                                                         float* __restrict__ pmaxo, float* __restrict__ psumo) {
  int e = blockIdx.x * 256 + threadIdx.x;  // e = b*1024 + c, grid 64
  int b = e >> 10, c = e & 1023;
  const float* bp = pp + ((size_t)b * 64) * EMB + c;
  const float* bs = ps + ((size_t)b * 64) * EMB + c;
  float mx = 0.f, sm = 0.f;
  #pragma unroll 8
  for (int tl = 0; tl < 64; ++tl) {
    float v = bp[(size_t)tl * EMB];
    float s = bs[(size_t)tl * EMB];
    mx = mx > v ? mx : v;
    sm += s;
  }
  pmaxo[e] = mx;
  psumo[e] = sm;
}

// ---------------- final linear: pooled[16,2048] @ W4 + b4 -> out[16,7] ----------------
__global__ __launch_bounds__(64) void final_kernel(const float* __restrict__ pmax, const float* __restrict__ psum,
    const float* __restrict__ W4, const float* __restrict__ b4, float* __restrict__ out) {
  int b = blockIdx.x, t = threadIdx.x;
  #pragma unroll
  for (int o = 0; o < OUT; ++o) {
    float acc = 0.f;
    for (int tt = t; tt < 2 * EMB; tt += 64) {
      float p = (tt < EMB) ? pmax[(size_t)b * EMB + tt]
                           : psum[(size_t)b * EMB + tt - EMB] * (1.0f / (float)NPT);
      acc += p * W4[(size_t)tt * OUT + o];
    }
    #pragma unroll
    for (int off = 32; off > 0; off >>= 1) acc += __shfl_down(acc, off);
    if (t == 0) out[b * OUT + o] = acc + b4[o];
  }
}

extern "C" void kernel_launch(void* const* d_in, const int* in_sizes, int n_in,
                              void* d_out, int out_size, void* d_ws, size_t ws_size,
                              hipStream_t stream) {
  const float* pos = (const float*)d_in[0];
  const float* W1 = (const float*)d_in[1];  const float* b1 = (const float*)d_in[2];
  const float* g1 = (const float*)d_in[3];  const float* be1 = (const float*)d_in[4];
  const float* W2 = (const float*)d_in[5];  const float* b2 = (const float*)d_in[6];
  const float* g2 = (const float*)d_in[7];  const float* be2 = (const float*)d_in[8];
  const float* W3 = (const float*)d_in[9];  const float* b3 = (const float*)d_in[10];
  const float* g3 = (const float*)d_in[11]; const float* be3 = (const float*)d_in[12];
  const float* W4 = (const float*)d_in[13]; const float* b4 = (const float*)d_in[14];
  float* out = (float*)d_out;

  // ---- workspace layout, total ~25.6 MiB (proven safe in rounds 4/5) ----
  char* ws = (char*)d_ws;
  unsigned short* idx = (unsigned short*)ws;               // NEDGE u16 = 1.25 MiB
  __half2* am = (__half2*)(ws + (size_t)NEDGE * 2);        // NNODE*C2 half2 = 16 MiB
  char* smallbase = (char*)(am + (size_t)NNODE * C2);

  double* dstats  = (double*)smallbase;           // 32 (27 used)
  double* G2      = dstats + 32;                  // 16384
  double* nodesum = G2 + 16384;                   // 128
  float* scale1 = (float*)(nodesum + 128);
  float* shift1 = scale1 + C1;
  float* scale2 = shift1 + C1;
  float* shift2 = scale2 + C2;
  float* scale3 = shift2 + C2;
  float* shift3 = scale3 + EMB;
  float* pooledmax = shift3 + EMB;                // 16*1024
  float* pooledsum = pooledmax + NB * EMB;        // 16*1024
  char* scratch = (char*)(pooledsum + NB * EMB);
  // lifetime-disjoint overlays on one ~8.45 MiB slab:
  double* eg_part  = (double*)scratch;            // 4096*256*8  = 8.00 MiB (edge2 -> finalize2)
  float* gram_part = (float*)scratch;             // 128*16512*4 = 8.06 MiB (gram_part -> gram_reduce)
  float* pp        = (float*)scratch;             // 1024*1024*4 = 4 MiB    (apply3pool -> poolreduce)
  float* psb       = pp + (size_t)1024 * EMB;     // 4 MiB

  hipMemsetAsync(dstats, 0, 32 * sizeof(double), stream);

  knn_kernel<<<NB * NPT / 4, 256, 0, stream>>>(pos, idx);
  statse_kernel<<<512, 256, 0, stream>>>(pos, idx, dstats);
  finalize1_kernel<<<1, 64, 0, stream>>>(dstats, W1, b1, g1, be1, scale1, shift1);
  edge2_kernel<<<E2_BLOCKS, 256, 0, stream>>>(pos, idx, W1, b1, scale1, shift1, W2, b2, am, eg_part);
  finalize2_kernel<<<C2, 256, 0, stream>>>(eg_part, g2, be2, scale2, shift2);
  gram_part_kernel<<<GRAM_GRID, 256, 0, stream>>>(am, scale2, shift2, gram_part);
  gram_reduce_kernel<<<(GRAM_ELEMS + 255) / 256, 256, 0, stream>>>(gram_part, G2, nodesum);
  finalize3_kernel<<<EMB, 128, 0, stream>>>(G2, nodesum, W3, b3, g3, be3, scale3, shift3);
  apply3pool_kernel<<<dim3(1024, 2), 256, 0, stream>>>(am, scale2, shift2, W3, b3, scale3, shift3, pp, psb);
  poolreduce_kernel<<<NB * EMB / 256, 256, 0, stream>>>(pp, psb, pooledmax, pooledsum);
  final_kernel<<<NB, 64, 0, stream>>>(pooledmax, pooledsum, W4, b4, out);
}

// Round 7
// 759.180 us; speedup vs baseline: 1.1845x; 1.1845x over previous
//
#include <hip/hip_runtime.h>
#include <hip/hip_fp16.h>
#include <float.h>

// ---- fixed problem shape ----
constexpr int NB  = 16;     // batch (clouds)
constexpr int NPT = 2048;   // points per cloud
constexpr int KK  = 20;     // kNN
constexpr int NEDGE = NB * NPT * KK;       // 655360
constexpr int C1 = 64, C2 = 128, EMB = 1024, OUT = 7;
constexpr int NNODE = NB * NPT;            // 32768
constexpr int E2_BLOCKS = 1024;            // edge2 grid (4 tiles each)
constexpr int N_E2_PART = 8192;            // edge2 stat partials (1024 blocks x 8 row-groups)
constexpr int GRAM_GRID = 128;
constexpr int GRAM_ELEMS = C2 * C2 + C2;   // 16512 (Gram + colsum)
__device__ constexpr double R1d = (double)NEDGE;       // BN1/BN2 row count
__device__ constexpr double R3d = (double)(NB * NPT);  // BN3 row count
constexpr unsigned long long INF64 = ~0ull;

using half2_t = _Float16 __attribute__((ext_vector_type(2)));
using half8_t = _Float16 __attribute__((ext_vector_type(8)));

static __device__ __forceinline__ float fdot2f(half2_t a, half2_t b, float c) {
#if __has_builtin(__builtin_amdgcn_fdot2)
  return __builtin_amdgcn_fdot2(a, b, c, false);
#else
  return c + (float)a[0] * (float)b[0] + (float)a[1] * (float)b[1];
#endif
}

// ---------------- kNN: one wave per query, keys fully register-resident ----------------
// key[] must be indexed ONLY by compile-time constants (full unroll) or the
// array lands in scratch (round-4 profile: 525 MB spill writes, 278 us).
__global__ __launch_bounds__(256) void knn_kernel(const float* __restrict__ pos, unsigned short* __restrict__ idxo) {
  int t = threadIdx.x;
  int lane = t & 63, w = t >> 6;
  int bn = blockIdx.x * 4 + w;            // 8192 blocks x 4 waves = 32768 queries
  int b = bn >> 11, n = bn & (NPT - 1);
  const float* pb = pos + (size_t)b * NPT * 3;
  float xn = pb[n * 3], yn = pb[n * 3 + 1], zn = pb[n * 3 + 2];
  float sqn = xn * xn + yn * yn + zn * zn;

  unsigned long long key[32];
  #pragma unroll
  for (int i = 0; i < 32; ++i) {
    int m = i * 64 + lane;
    float xm = pb[m * 3], ym = pb[m * 3 + 1], zm = pb[m * 3 + 2];
    float sqm = xm * xm + ym * ym + zm * zm;
    float dt = xn * xm + yn * ym + zn * zm;
    float d = sqn + sqm - 2.0f * dt;
    unsigned ub = __float_as_uint(d);
    ub = (ub & 0x80000000u) ? ~ub : (ub | 0x80000000u);  // order-preserving map
    key[i] = ((unsigned long long)ub << 32) | (unsigned long long)(unsigned)m;
  }

  unsigned long long T = 0;
  int myidx = 0;
  for (int r = 0; r < KK; ++r) {
    unsigned long long t0[16];
    #pragma unroll
    for (int i = 0; i < 16; ++i) {
      unsigned long long a = key[2 * i]     >= T ? key[2 * i]     : INF64;
      unsigned long long c = key[2 * i + 1] >= T ? key[2 * i + 1] : INF64;
      t0[i] = a < c ? a : c;
    }
    #pragma unroll
    for (int s = 8; s > 0; s >>= 1)
      #pragma unroll
      for (int i = 0; i < 8; ++i)
        if (i < s) t0[i] = t0[i] < t0[i + s] ? t0[i] : t0[i + s];
    unsigned long long best = t0[0];
    #pragma unroll
    for (int off = 32; off > 0; off >>= 1) {
      unsigned long long o = (unsigned long long)__shfl_xor((long long)best, off, 64);
      best = best < o ? best : o;
    }
    if (lane == r) myidx = (int)(unsigned)(best & 0xffffffffull);
    T = best + 1;
  }
  if (lane < KK) idxo[(size_t)bn * KK + lane] = (unsigned short)myidx;
}

// ---------------- edge-feature first/second moments (6 + 21 doubles) ----------------
__global__ __launch_bounds__(256) void statse_kernel(const float* __restrict__ pos, const unsigned short* __restrict__ idx,
                                                     double* __restrict__ dstats) {
  float acc[27];
  #pragma unroll
  for (int i = 0; i < 27; ++i) acc[i] = 0.f;
  int t = threadIdx.x;
  for (int e = blockIdx.x * 256 + t; e < NEDGE; e += gridDim.x * 256) {
    int bn = e / KK;
    int b = bn >> 11, n = bn & (NPT - 1);
    int j = idx[e];
    const float* pb = pos + (size_t)b * NPT * 3;
    float f[6];
    f[0] = pb[n * 3]; f[1] = pb[n * 3 + 1]; f[2] = pb[n * 3 + 2];
    f[3] = pb[j * 3] - f[0]; f[4] = pb[j * 3 + 1] - f[1]; f[5] = pb[j * 3 + 2] - f[2];
    int p = 6;
    #pragma unroll
    for (int d = 0; d < 6; ++d) acc[d] += f[d];
    #pragma unroll
    for (int d = 0; d < 6; ++d)
      #pragma unroll
      for (int q = d; q < 6; ++q) { acc[p] += f[d] * f[q]; ++p; }
  }
  __shared__ float sred[4][27];
  int lane = t & 63, w = t >> 6;
  #pragma unroll
  for (int c = 0; c < 27; ++c) {
    float v = acc[c];
    #pragma unroll
    for (int off = 32; off > 0; off >>= 1) v += __shfl_down(v, off);
    if (lane == 0) sred[w][c] = v;
  }
  __syncthreads();
  if (t < 27) {
    double s = (double)sred[0][t] + (double)sred[1][t] + (double)sred[2][t] + (double)sred[3][t];
    atomicAdd(&dstats[t], s);
  }
}

// ---------------- BN1 coeffs from moments ----------------
__global__ void finalize1_kernel(const double* __restrict__ dstats, const float* __restrict__ W1,
                                 const float* __restrict__ b1, const float* __restrict__ g1,
                                 const float* __restrict__ be1, float* __restrict__ scale1,
                                 float* __restrict__ shift1) {
  int c = threadIdx.x;  // 64
  double m1[6], M2[6][6];
  for (int d = 0; d < 6; ++d) m1[d] = dstats[d];
  int p = 6;
  for (int d = 0; d < 6; ++d)
    for (int q = d; q < 6; ++q) { M2[d][q] = dstats[p]; M2[q][d] = dstats[p]; ++p; }
  double w[6];
  for (int d = 0; d < 6; ++d) w[d] = W1[d * C1 + c];
  double wm = 0, quad = 0;
  for (int d = 0; d < 6; ++d) wm += w[d] * m1[d];
  for (int d = 0; d < 6; ++d) {
    double s = 0;
    for (int q = 0; q < 6; ++q) s += M2[d][q] * w[q];
    quad += w[d] * s;
  }
  double bb = b1[c];
  double mean = wm / R1d + bb;
  double E2 = (quad + 2.0 * bb * wm) / R1d + bb * bb;
  double var = E2 - mean * mean;
  double sc = (double)g1[c] / sqrt(var + 1e-5);
  scale1[c] = (float)sc;
  shift1[c] = (float)((double)be1[c] - mean * sc);
}

// ---------------- fused edge pass v3: fp16 LDS + v_dot2, 4 blocks/CU ----------------
// 8-node (160-edge) tiles; h and W2 packed as half2 pairs along K in LDS
// (40.7 KB total -> 4 blocks/CU). Thread = (row-group rg, channel-quad cq):
// acc[20][4] f32 via fdot2. Per-node max/min thread-local; stats partials f32.
__global__ __launch_bounds__(256) void edge2_kernel(const float* __restrict__ pos, const unsigned short* __restrict__ idx,
    const float* __restrict__ W1, const float* __restrict__ b1,
    const float* __restrict__ scale1, const float* __restrict__ shift1,
    const float* __restrict__ W2, const float* __restrict__ b2,
    __half2* __restrict__ am, float* __restrict__ part) {
  constexpr int TROWS = 160;              // 8 nodes x 20 edges
  __shared__ half2_t w2p[32 * C2];        // 16 KiB  (pair jp, col c) = (W2[2jp][c], W2[2jp+1][c])
  __shared__ half2_t hp[TROWS * 32];      // 20 KiB  (row, pair jp)
  __shared__ float es[TROWS * 6];         // 3.75 KiB
  int t = threadIdx.x;

  // stage W2 packed-pairs once per block
  for (int i = t; i < 32 * C2; i += 256) {
    int jp = i >> 7, c = i & 127;
    float w0 = W2[(2 * jp) * C2 + c], w1 = W2[(2 * jp + 1) * C2 + c];
    half2_t hw; hw[0] = (_Float16)w0; hw[1] = (_Float16)w1;
    w2p[i] = hw;
  }
  // P2 thread mapping: fixed channel pair jp2 = t&31 -> columns 2*jp2, 2*jp2+1
  int jp2 = t & 31;
  float w1a[6], w1b[6];
  #pragma unroll
  for (int d = 0; d < 6; ++d) {
    w1a[d] = W1[d * C1 + 2 * jp2];
    w1b[d] = W1[d * C1 + 2 * jp2 + 1];
  }
  float b1a = b1[2 * jp2], s1a = scale1[2 * jp2], sh1a = shift1[2 * jp2];
  float b1b = b1[2 * jp2 + 1], s1b = scale1[2 * jp2 + 1], sh1b = shift1[2 * jp2 + 1];
  // P3 thread mapping: node row-group rg, channel quad c0..c0+3
  int cq = t & 31, rg = t >> 5;
  int c0 = cq * 4;
  float4 b2q = *(const float4*)&b2[c0];
  float accs[4] = {0, 0, 0, 0}, accq[4] = {0, 0, 0, 0};

  for (int tile = blockIdx.x; tile < NNODE / 8; tile += E2_BLOCKS) {
    // P1: gather 160 edges x 6 comps
    for (int i = t; i < TROWS * 6; i += 256) {
      int r = i / 6, comp = i - r * 6;
      int e = tile * TROWS + r;
      int bn = e / KK;
      int b = bn >> 11, n = bn & (NPT - 1);
      int j = idx[e];
      const float* pb = pos + (size_t)b * NPT * 3;
      float v;
      if (comp < 3) v = pb[n * 3 + comp];
      else          v = pb[j * 3 + comp - 3] - pb[n * 3 + comp - 3];
      es[i] = v;
    }
    __syncthreads();
    // P2: h = relu(bn1(e @ W1)), two channels per thread, packed half2
    #pragma unroll
    for (int i = 0; i < 20; ++i) {
      int row = (t >> 5) + 8 * i;
      float a = b1a, bvl = b1b;
      #pragma unroll
      for (int d = 0; d < 6; ++d) {
        float ev = es[row * 6 + d];
        a += ev * w1a[d];
        bvl += ev * w1b[d];
      }
      a = a * s1a + sh1a;   a = a > 0.f ? a : 0.f;
      bvl = bvl * s1b + sh1b; bvl = bvl > 0.f ? bvl : 0.f;
      half2_t hh; hh[0] = (_Float16)a; hh[1] = (_Float16)bvl;
      hp[row * 32 + jp2] = hh;
    }
    __syncthreads();
    // P3: a2 = h @ W2, register-blocked 20 rows x 4 cols via fdot2
    float acc[20][4];
    #pragma unroll
    for (int r = 0; r < 20; ++r) { acc[r][0] = 0.f; acc[r][1] = 0.f; acc[r][2] = 0.f; acc[r][3] = 0.f; }
    int hbase = rg * 20 * 32;
    #pragma unroll
    for (int step = 0; step < 8; ++step) {
      half8_t wv[4];
      #pragma unroll
      for (int p = 0; p < 4; ++p)
        wv[p] = *(const half8_t*)&w2p[(step * 4 + p) * C2 + c0];
      #pragma unroll
      for (int r = 0; r < 20; ++r) {
        half8_t hv = *(const half8_t*)&hp[hbase + r * 32 + step * 4];
        #pragma unroll
        for (int p = 0; p < 4; ++p) {
          half2_t hpair; hpair[0] = hv[2 * p]; hpair[1] = hv[2 * p + 1];
          #pragma unroll
          for (int k = 0; k < 4; ++k) {
            half2_t wpair; wpair[0] = wv[p][2 * k]; wpair[1] = wv[p][2 * k + 1];
            acc[r][k] = fdot2f(hpair, wpair, acc[r][k]);
          }
        }
      }
    }
    // epilogue: bias, f32 stats, thread-local node max/min
    float sm[4] = {0, 0, 0, 0}, sq[4] = {0, 0, 0, 0};
    float mx[4] = {-FLT_MAX, -FLT_MAX, -FLT_MAX, -FLT_MAX};
    float mn[4] = {FLT_MAX, FLT_MAX, FLT_MAX, FLT_MAX};
    #pragma unroll
    for (int r = 0; r < 20; ++r) {
      float a0 = acc[r][0] + b2q.x;
      float a1 = acc[r][1] + b2q.y;
      float a2 = acc[r][2] + b2q.z;
      float a3 = acc[r][3] + b2q.w;
      sm[0] += a0; sq[0] += a0 * a0; mx[0] = fmaxf(mx[0], a0); mn[0] = fminf(mn[0], a0);
      sm[1] += a1; sq[1] += a1 * a1; mx[1] = fmaxf(mx[1], a1); mn[1] = fminf(mn[1], a1);
      sm[2] += a2; sq[2] += a2 * a2; mx[2] = fmaxf(mx[2], a2); mn[2] = fminf(mn[2], a2);
      sm[3] += a3; sq[3] += a3 * a3; mx[3] = fmaxf(mx[3], a3); mn[3] = fminf(mn[3], a3);
    }
    #pragma unroll
    for (int k = 0; k < 4; ++k) { accs[k] += sm[k]; accq[k] += sq[k]; }
    int node = tile * 8 + rg;
    __half2* dst = &am[(size_t)node * C2 + c0];
    dst[0] = __floats2half2_rn(mx[0], mn[0]);
    dst[1] = __floats2half2_rn(mx[1], mn[1]);
    dst[2] = __floats2half2_rn(mx[2], mn[2]);
    dst[3] = __floats2half2_rn(mx[3], mn[3]);
    __syncthreads();  // protect es/hp before next tile's writes
  }
  // write per-(block,rg) f32 partials: part[(blk*8+rg)*256 + {c | 128+c}]
  float* base = part + ((size_t)blockIdx.x * 8 + rg) * 256;
  #pragma unroll
  for (int k = 0; k < 4; ++k) {
    base[c0 + k] = accs[k];
    base[128 + c0 + k] = accq[k];
  }
}

// ---------------- BN2 finalize: reduce f32 partials in f64, one block per channel ----------------
__global__ __launch_bounds__(256) void finalize2_kernel(const float* __restrict__ part,
                                 const float* __restrict__ g2w, const float* __restrict__ be2,
                                 float* __restrict__ scale2, float* __restrict__ shift2) {
  int c = blockIdx.x;   // 128
  int t = threadIdx.x;  // 256
  double s = 0, q = 0;
  for (int i = t; i < N_E2_PART; i += 256) {
    s += (double)part[(size_t)i * 256 + c];
    q += (double)part[(size_t)i * 256 + 128 + c];
  }
  __shared__ double shs[256], shq[256];
  shs[t] = s; shq[t] = q; __syncthreads();
  for (int off = 128; off > 0; off >>= 1) {
    if (t < off) { shs[t] += shs[t + off]; shq[t] += shq[t + off]; }
    __syncthreads();
  }
  if (t == 0) {
    double mean = shs[0] / R1d;
    double var = shq[0] / R1d - mean * mean;
    double sc = (double)g2w[c] / sqrt(var + 1e-5);
    scale2[c] = (float)sc;
    shift2[c] = (float)((double)be2[c] - mean * sc);
  }
}

// node value on the fly: relu(scale * (scale>=0 ? max : min) + shift)
static __device__ __forceinline__ float node_val(__half2 h2, float s, float sh) {
  float A = __low2float(h2), N = __high2float(h2);
  float v = (s >= 0.f ? A : N) * s + sh;
  return v > 0.f ? v : 0.f;
}

// ---------------- Gram partials: BN2 applied on the fly; private 128x128 partial + colsum ----------------
__global__ __launch_bounds__(256) void gram_part_kernel(const __half2* __restrict__ am,
                                                        const float* __restrict__ scale2, const float* __restrict__ shift2,
                                                        float* __restrict__ part) {
  __shared__ float tile[64 * C2];  // 32 KiB
  __shared__ float s_s[C2], s_h[C2];
  int t = threadIdx.x;
  if (t < C2) { s_s[t] = scale2[t]; s_h[t] = shift2[t]; }
  __syncthreads();
  int i = t & 127, jh = t >> 7;
  float acc[64];
  #pragma unroll
  for (int u = 0; u < 64; ++u) acc[u] = 0.f;
  float csum = 0.f;
  for (int tl = blockIdx.x; tl < NNODE / 64; tl += GRAM_GRID) {
    const __half2* a2 = am + (size_t)tl * 64 * C2;
    #pragma unroll
    for (int q = 0; q < 32; ++q) {
      int e = q * 256 + t;
      int c = e & 127;
      tile[e] = node_val(a2[e], s_s[c], s_h[c]);
    }
    __syncthreads();
    #pragma unroll 4
    for (int r = 0; r < 64; ++r) {
      float xi = tile[r * C2 + i];
      const float4* row4 = (const float4*)&tile[r * C2 + jh * 64];
      #pragma unroll
      for (int u4 = 0; u4 < 16; ++u4) {
        float4 v = row4[u4];
        acc[u4 * 4 + 0] += xi * v.x;
        acc[u4 * 4 + 1] += xi * v.y;
        acc[u4 * 4 + 2] += xi * v.z;
        acc[u4 * 4 + 3] += xi * v.w;
      }
    }
    if (t < 128) {
      #pragma unroll 8
      for (int r = 0; r < 64; ++r) csum += tile[r * C2 + t];
    }
    __syncthreads();
  }
  float* pb = part + (size_t)blockIdx.x * GRAM_ELEMS;
  float4* pout = (float4*)(pb + (size_t)i * C2 + jh * 64);
  #pragma unroll
  for (int u4 = 0; u4 < 16; ++u4)
    pout[u4] = make_float4(acc[u4 * 4], acc[u4 * 4 + 1], acc[u4 * 4 + 2], acc[u4 * 4 + 3]);
  if (t < 128) pb[C2 * C2 + t] = csum;
}

// ---------------- Gram reduce: sum partials -> f64 G2 + nodesum ----------------
__global__ __launch_bounds__(256) void gram_reduce_kernel(const float* __restrict__ part,
                                                          double* __restrict__ G2, double* __restrict__ nodesum) {
  int e = blockIdx.x * 256 + threadIdx.x;
  if (e >= GRAM_ELEMS) return;
  double s = 0;
  for (int p = 0; p < GRAM_GRID; ++p) s += (double)part[(size_t)p * GRAM_ELEMS + e];
  if (e < C2 * C2) G2[e] = s;
  else nodesum[e - C2 * C2] = s;
}

// ---------------- BN3 coeffs from Gram ----------------
__global__ __launch_bounds__(128) void finalize3_kernel(const double* __restrict__ G2, const double* __restrict__ nodesum,
    const float* __restrict__ W3, const float* __restrict__ b3,
    const float* __restrict__ g3, const float* __restrict__ be3,
    float* __restrict__ scale3, float* __restrict__ shift3) {
  int c = blockIdx.x;   // 1024 channels
  int t = threadIdx.x;  // 128
  __shared__ double wsh[128];
  __shared__ double sh[128];
  double w = W3[(size_t)t * EMB + c];
  wsh[t] = w;
  __syncthreads();
  double rowdot = 0;
  for (int j = 0; j < 128; ++j) rowdot += G2[(size_t)j * C2 + t] * wsh[j];
  sh[t] = w * rowdot;
  __syncthreads();
  for (int off = 64; off > 0; off >>= 1) { if (t < off) sh[t] += sh[t + off]; __syncthreads(); }
  double quad = sh[0];
  __syncthreads();
  sh[t] = w * nodesum[t];
  __syncthreads();
  for (int off = 64; off > 0; off >>= 1) { if (t < off) sh[t] += sh[t + off]; __syncthreads(); }
  if (t == 0) {
    double wm = sh[0];
    double bb = b3[c];
    double mean = wm / R3d + bb;
    double E2 = (quad + 2.0 * bb * wm) / R3d + bb * bb;
    double var = E2 - mean * mean;
    double sc = (double)g3[c] / sqrt(var + 1e-5);
    scale3[c] = (float)sc;
    shift3[c] = (float)((double)be3[c] - mean * sc);
  }
}

// ---------------- linear1 apply (BN2 on the fly) + BN3 + ReLU -> per-row-tile partial max/sum ----------------
__global__ __launch_bounds__(256) void apply3pool_kernel(const __half2* __restrict__ am,
    const float* __restrict__ scale2, const float* __restrict__ shift2,
    const float* __restrict__ W3, const float* __restrict__ b3,
    const float* __restrict__ scale3, const float* __restrict__ shift3,
    float* __restrict__ pp, float* __restrict__ ps) {
  __shared__ float tile[32 * C2];  // 16 KiB
  __shared__ float s_s[C2], s_h[C2];
  int rt = blockIdx.x;  // 1024 row tiles of 32 rows
  int ct = blockIdx.y;  // 2 column halves
  int t = threadIdx.x;
  if (t < C2) { s_s[t] = scale2[t]; s_h[t] = shift2[t]; }
  __syncthreads();
  int c0 = ct * 512 + t;
  int c1 = c0 + 256;
  const __half2* a2 = am + (size_t)rt * 32 * C2;
  #pragma unroll
  for (int q = 0; q < 16; ++q) {
    int e = q * 256 + t;
    int c = e & 127;
    tile[e] = node_val(a2[e], s_s[c], s_h[c]);
  }
  __syncthreads();
  float a0[32], a1[32];
  #pragma unroll
  for (int r = 0; r < 32; ++r) { a0[r] = 0.f; a1[r] = 0.f; }
  for (int j = 0; j < 128; j += 4) {
    float w00 = W3[(size_t)j * EMB + c0], w01 = W3[(size_t)(j + 1) * EMB + c0];
    float w02 = W3[(size_t)(j + 2) * EMB + c0], w03 = W3[(size_t)(j + 3) * EMB + c0];
    float w10 = W3[(size_t)j * EMB + c1], w11 = W3[(size_t)(j + 1) * EMB + c1];
    float w12 = W3[(size_t)(j + 2) * EMB + c1], w13 = W3[(size_t)(j + 3) * EMB + c1];
    #pragma unroll
    for (int r = 0; r < 32; ++r) {
      float4 v = *(const float4*)&tile[r * C2 + j];
      a0[r] += v.x * w00 + v.y * w01 + v.z * w02 + v.w * w03;
      a1[r] += v.x * w10 + v.y * w11 + v.z * w12 + v.w * w13;
    }
  }
  float b30 = b3[c0], s30 = scale3[c0], sh30 = shift3[c0];
  float b31 = b3[c1], s31 = scale3[c1], sh31 = shift3[c1];
  float mx0 = 0.f, sm0 = 0.f, mx1 = 0.f, sm1 = 0.f;
  #pragma unroll
  for (int r = 0; r < 32; ++r) {
    float x0 = (a0[r] + b30) * s30 + sh30; x0 = x0 > 0.f ? x0 : 0.f; mx0 = mx0 > x0 ? mx0 : x0; sm0 += x0;
    float x1 = (a1[r] + b31) * s31 + sh31; x1 = x1 > 0.f ? x1 : 0.f; mx1 = mx1 > x1 ? mx1 : x1; sm1 += x1;
  }
  float* ppb = pp + (size_t)rt * EMB;
  float* psb = ps + (size_t)rt * EMB;
  ppb[c0] = mx0; psb[c0] = sm0;
  ppb[c1] = mx1; psb[c1] = sm1;
}

// ---------------- pool reduce: per (b,c) max/sum over 64 row tiles ----------------
__global__ __launch_bounds__(256) void poolreduce_kernel(const float* __restrict__ pp, const float* __restrict__ ps,
                                                         float* __restrict__ pmaxo, float* __restrict__ psumo) {
  int e = blockIdx.x * 256 + threadIdx.x;  // e = b*1024 + c, grid 64
  int b = e >> 10, c = e & 1023;
  const float* bp = pp + ((size_t)b * 64) * EMB + c;
  const float* bs = ps + ((size_t)b * 64) * EMB + c;
  float mx = 0.f, sm = 0.f;
  #pragma unroll 8
  for (int tl = 0; tl < 64; ++tl) {
    float v = bp[(size_t)tl * EMB];
    float s = bs[(size_t)tl * EMB];
    mx = mx > v ? mx : v;
    sm += s;
  }
  pmaxo[e] = mx;
  psumo[e] = sm;
}

// ---------------- final linear: pooled[16,2048] @ W4 + b4 -> out[16,7] ----------------
__global__ __launch_bounds__(64) void final_kernel(const float* __restrict__ pmax, const float* __restrict__ psum,
    const float* __restrict__ W4, const float* __restrict__ b4, float* __restrict__ out) {
  int b = blockIdx.x, t = threadIdx.x;
  #pragma unroll
  for (int o = 0; o < OUT; ++o) {
    float acc = 0.f;
    for (int tt = t; tt < 2 * EMB; tt += 64) {
      float p = (tt < EMB) ? pmax[(size_t)b * EMB + tt]
                           : psum[(size_t)b * EMB + tt - EMB] * (1.0f / (float)NPT);
      acc += p * W4[(size_t)tt * OUT + o];
    }
    #pragma unroll
    for (int off = 32; off > 0; off >>= 1) acc += __shfl_down(acc, off);
    if (t == 0) out[b * OUT + o] = acc + b4[o];
  }
}

extern "C" void kernel_launch(void* const* d_in, const int* in_sizes, int n_in,
                              void* d_out, int out_size, void* d_ws, size_t ws_size,
                              hipStream_t stream) {
  const float* pos = (const float*)d_in[0];
  const float* W1 = (const float*)d_in[1];  const float* b1 = (const float*)d_in[2];
  const float* g1 = (const float*)d_in[3];  const float* be1 = (const float*)d_in[4];
  const float* W2 = (const float*)d_in[5];  const float* b2 = (const float*)d_in[6];
  const float* g2 = (const float*)d_in[7];  const float* be2 = (const float*)d_in[8];
  const float* W3 = (const float*)d_in[9];  const float* b3 = (const float*)d_in[10];
  const float* g3 = (const float*)d_in[11]; const float* be3 = (const float*)d_in[12];
  const float* W4 = (const float*)d_in[13]; const float* b4 = (const float*)d_in[14];
  float* out = (float*)d_out;

  // ---- workspace layout, total ~25.6 MiB (proven safe in rounds 4-6) ----
  char* ws = (char*)d_ws;
  unsigned short* idx = (unsigned short*)ws;               // NEDGE u16 = 1.25 MiB
  __half2* am = (__half2*)(ws + (size_t)NEDGE * 2);        // NNODE*C2 half2 = 16 MiB
  char* smallbase = (char*)(am + (size_t)NNODE * C2);

  double* dstats  = (double*)smallbase;           // 32 (27 used)
  double* G2      = dstats + 32;                  // 16384
  double* nodesum = G2 + 16384;                   // 128
  float* scale1 = (float*)(nodesum + 128);
  float* shift1 = scale1 + C1;
  float* scale2 = shift1 + C1;
  float* shift2 = scale2 + C2;
  float* scale3 = shift2 + C2;
  float* shift3 = scale3 + EMB;
  float* pooledmax = shift3 + EMB;                // 16*1024
  float* pooledsum = pooledmax + NB * EMB;        // 16*1024
  char* scratch = (char*)(pooledsum + NB * EMB);
  // lifetime-disjoint overlays on one ~8.45 MiB slab:
  float* eg_part   = (float*)scratch;             // 8192*256*4  = 8.00 MiB (edge2 -> finalize2)
  float* gram_part = (float*)scratch;             // 128*16512*4 = 8.06 MiB (gram_part -> gram_reduce)
  float* pp        = (float*)scratch;             // 1024*1024*4 = 4 MiB    (apply3pool -> poolreduce)
  float* psb       = pp + (size_t)1024 * EMB;     // 4 MiB

  hipMemsetAsync(dstats, 0, 32 * sizeof(double), stream);

  knn_kernel<<<NB * NPT / 4, 256, 0, stream>>>(pos, idx);
  statse_kernel<<<512, 256, 0, stream>>>(pos, idx, dstats);
  finalize1_kernel<<<1, 64, 0, stream>>>(dstats, W1, b1, g1, be1, scale1, shift1);
  edge2_kernel<<<E2_BLOCKS, 256, 0, stream>>>(pos, idx, W1, b1, scale1, shift1, W2, b2, am, eg_part);
  finalize2_kernel<<<C2, 256, 0, stream>>>(eg_part, g2, be2, scale2, shift2);
  gram_part_kernel<<<GRAM_GRID, 256, 0, stream>>>(am, scale2, shift2, gram_part);
  gram_reduce_kernel<<<(GRAM_ELEMS + 255) / 256, 256, 0, stream>>>(gram_part, G2, nodesum);
  finalize3_kernel<<<EMB, 128, 0, stream>>>(G2, nodesum, W3, b3, g3, be3, scale3, shift3);
  apply3pool_kernel<<<dim3(1024, 2), 256, 0, stream>>>(am, scale2, shift2, W3, b3, scale3, shift3, pp, psb);
  poolreduce_kernel<<<NB * EMB / 256, 256, 0, stream>>>(pp, psb, pooledmax, pooledsum);
  final_kernel<<<NB, 64, 0, stream>>>(pooledmax, pooledsum, W4, b4, out);
}

// Round 8
// 712.665 us; speedup vs baseline: 1.2618x; 1.0653x over previous
//
#include <hip/hip_runtime.h>
#include <hip/hip_fp16.h>
#include <float.h>

// ---- fixed problem shape ----
constexpr int NB  = 16;     // batch (clouds)
constexpr int NPT = 2048;   // points per cloud
constexpr int KK  = 20;     // kNN
constexpr int NEDGE = NB * NPT * KK;       // 655360
constexpr int C1 = 64, C2 = 128, EMB = 1024, OUT = 7;
constexpr int NNODE = NB * NPT;            // 32768
constexpr int E2_BLOCKS = 1024;            // edge2 grid (4 tiles each)
constexpr int N_E2_PART = 8192;            // edge2 stat partials (1024 blocks x 8 row-groups)
constexpr int GRAM_GRID = 128;
constexpr int GRAM_ELEMS = C2 * C2 + C2;   // 16512 (Gram + colsum)
__device__ constexpr double R1d = (double)NEDGE;       // BN1/BN2 row count
__device__ constexpr double R3d = (double)(NB * NPT);  // BN3 row count
constexpr unsigned long long INF64 = ~0ull;

using half2_t = _Float16 __attribute__((ext_vector_type(2)));
using half8_t = _Float16 __attribute__((ext_vector_type(8)));

static __device__ __forceinline__ float fdot2f(half2_t a, half2_t b, float c) {
  return __builtin_amdgcn_fdot2(a, b, c, false);
}

// ---------------- kNN: one wave per query, keys fully register-resident ----------------
__global__ __launch_bounds__(256) void knn_kernel(const float* __restrict__ pos, unsigned short* __restrict__ idxo) {
  int t = threadIdx.x;
  int lane = t & 63, w = t >> 6;
  int bn = blockIdx.x * 4 + w;            // 8192 blocks x 4 waves = 32768 queries
  int b = bn >> 11, n = bn & (NPT - 1);
  const float* pb = pos + (size_t)b * NPT * 3;
  float xn = pb[n * 3], yn = pb[n * 3 + 1], zn = pb[n * 3 + 2];
  float sqn = xn * xn + yn * yn + zn * zn;

  unsigned long long key[32];
  #pragma unroll
  for (int i = 0; i < 32; ++i) {
    int m = i * 64 + lane;
    float xm = pb[m * 3], ym = pb[m * 3 + 1], zm = pb[m * 3 + 2];
    float sqm = xm * xm + ym * ym + zm * zm;
    float dt = xn * xm + yn * ym + zn * zm;
    float d = sqn + sqm - 2.0f * dt;
    unsigned ub = __float_as_uint(d);
    ub = (ub & 0x80000000u) ? ~ub : (ub | 0x80000000u);  // order-preserving map
    key[i] = ((unsigned long long)ub << 32) | (unsigned long long)(unsigned)m;
  }

  unsigned long long T = 0;
  int myidx = 0;
  for (int r = 0; r < KK; ++r) {
    unsigned long long t0[16];
    #pragma unroll
    for (int i = 0; i < 16; ++i) {
      unsigned long long a = key[2 * i]     >= T ? key[2 * i]     : INF64;
      unsigned long long c = key[2 * i + 1] >= T ? key[2 * i + 1] : INF64;
      t0[i] = a < c ? a : c;
    }
    #pragma unroll
    for (int s = 8; s > 0; s >>= 1)
      #pragma unroll
      for (int i = 0; i < 8; ++i)
        if (i < s) t0[i] = t0[i] < t0[i + s] ? t0[i] : t0[i + s];
    unsigned long long best = t0[0];
    #pragma unroll
    for (int off = 32; off > 0; off >>= 1) {
      unsigned long long o = (unsigned long long)__shfl_xor((long long)best, off, 64);
      best = best < o ? best : o;
    }
    if (lane == r) myidx = (int)(unsigned)(best & 0xffffffffull);
    T = best + 1;
  }
  if (lane < KK) idxo[(size_t)bn * KK + lane] = (unsigned short)myidx;
}

// ---------------- edge-feature first/second moments (6 + 21 doubles) ----------------
__global__ __launch_bounds__(256) void statse_kernel(const float* __restrict__ pos, const unsigned short* __restrict__ idx,
                                                     double* __restrict__ dstats) {
  float acc[27];
  #pragma unroll
  for (int i = 0; i < 27; ++i) acc[i] = 0.f;
  int t = threadIdx.x;
  for (int e = blockIdx.x * 256 + t; e < NEDGE; e += gridDim.x * 256) {
    int bn = e / KK;
    int b = bn >> 11, n = bn & (NPT - 1);
    int j = idx[e];
    const float* pb = pos + (size_t)b * NPT * 3;
    float f[6];
    f[0] = pb[n * 3]; f[1] = pb[n * 3 + 1]; f[2] = pb[n * 3 + 2];
    f[3] = pb[j * 3] - f[0]; f[4] = pb[j * 3 + 1] - f[1]; f[5] = pb[j * 3 + 2] - f[2];
    int p = 6;
    #pragma unroll
    for (int d = 0; d < 6; ++d) acc[d] += f[d];
    #pragma unroll
    for (int d = 0; d < 6; ++d)
      #pragma unroll
      for (int q = d; q < 6; ++q) { acc[p] += f[d] * f[q]; ++p; }
  }
  __shared__ float sred[4][27];
  int lane = t & 63, w = t >> 6;
  #pragma unroll
  for (int c = 0; c < 27; ++c) {
    float v = acc[c];
    #pragma unroll
    for (int off = 32; off > 0; off >>= 1) v += __shfl_down(v, off);
    if (lane == 0) sred[w][c] = v;
  }
  __syncthreads();
  if (t < 27) {
    double s = (double)sred[0][t] + (double)sred[1][t] + (double)sred[2][t] + (double)sred[3][t];
    atomicAdd(&dstats[t], s);
  }
}

// ---------------- BN1 coeffs from moments ----------------
__global__ void finalize1_kernel(const double* __restrict__ dstats, const float* __restrict__ W1,
                                 const float* __restrict__ b1, const float* __restrict__ g1,
                                 const float* __restrict__ be1, float* __restrict__ scale1,
                                 float* __restrict__ shift1) {
  int c = threadIdx.x;  // 64
  double m1[6], M2[6][6];
  for (int d = 0; d < 6; ++d) m1[d] = dstats[d];
  int p = 6;
  for (int d = 0; d < 6; ++d)
    for (int q = d; q < 6; ++q) { M2[d][q] = dstats[p]; M2[q][d] = dstats[p]; ++p; }
  double w[6];
  for (int d = 0; d < 6; ++d) w[d] = W1[d * C1 + c];
  double wm = 0, quad = 0;
  for (int d = 0; d < 6; ++d) wm += w[d] * m1[d];
  for (int d = 0; d < 6; ++d) {
    double s = 0;
    for (int q = 0; q < 6; ++q) s += M2[d][q] * w[q];
    quad += w[d] * s;
  }
  double bb = b1[c];
  double mean = wm / R1d + bb;
  double E2 = (quad + 2.0 * bb * wm) / R1d + bb * bb;
  double var = E2 - mean * mean;
  double sc = (double)g1[c] / sqrt(var + 1e-5);
  scale1[c] = (float)sc;
  shift1[c] = (float)((double)be1[c] - mean * sc);
}

// ---------------- W3 -> half2 K-paired pack: w3h[kp*EMB + c] = (W3[2kp][c], W3[2kp+1][c]) ----------------
__global__ __launch_bounds__(256) void packw3_kernel(const float* __restrict__ W3, half2_t* __restrict__ w3h) {
  int e = blockIdx.x * 256 + threadIdx.x;   // 65536 = 64 kp x 1024 c
  int kp = e >> 10, c = e & 1023;
  float w0 = W3[(size_t)(2 * kp) * EMB + c];
  float w1 = W3[(size_t)(2 * kp + 1) * EMB + c];
  half2_t h; h[0] = (_Float16)w0; h[1] = (_Float16)w1;
  w3h[e] = h;
}

// ---------------- fused edge pass v3: fp16 LDS + v_dot2, 4 blocks/CU ----------------
__global__ __launch_bounds__(256) void edge2_kernel(const float* __restrict__ pos, const unsigned short* __restrict__ idx,
    const float* __restrict__ W1, const float* __restrict__ b1,
    const float* __restrict__ scale1, const float* __restrict__ shift1,
    const float* __restrict__ W2, const float* __restrict__ b2,
    __half2* __restrict__ am, float* __restrict__ part) {
  constexpr int TROWS = 160;              // 8 nodes x 20 edges
  __shared__ half2_t w2p[32 * C2];        // 16 KiB  (pair jp, col c) = (W2[2jp][c], W2[2jp+1][c])
  __shared__ half2_t hp[TROWS * 32];      // 20 KiB  (row, pair jp)
  __shared__ float es[TROWS * 6];         // 3.75 KiB
  int t = threadIdx.x;

  for (int i = t; i < 32 * C2; i += 256) {
    int jp = i >> 7, c = i & 127;
    float w0 = W2[(2 * jp) * C2 + c], w1 = W2[(2 * jp + 1) * C2 + c];
    half2_t hw; hw[0] = (_Float16)w0; hw[1] = (_Float16)w1;
    w2p[i] = hw;
  }
  int jp2 = t & 31;
  float w1a[6], w1b[6];
  #pragma unroll
  for (int d = 0; d < 6; ++d) {
    w1a[d] = W1[d * C1 + 2 * jp2];
    w1b[d] = W1[d * C1 + 2 * jp2 + 1];
  }
  float b1a = b1[2 * jp2], s1a = scale1[2 * jp2], sh1a = shift1[2 * jp2];
  float b1b = b1[2 * jp2 + 1], s1b = scale1[2 * jp2 + 1], sh1b = shift1[2 * jp2 + 1];
  int cq = t & 31, rg = t >> 5;
  int c0 = cq * 4;
  float4 b2q = *(const float4*)&b2[c0];
  float accs[4] = {0, 0, 0, 0}, accq[4] = {0, 0, 0, 0};

  for (int tile = blockIdx.x; tile < NNODE / 8; tile += E2_BLOCKS) {
    for (int i = t; i < TROWS * 6; i += 256) {
      int r = i / 6, comp = i - r * 6;
      int e = tile * TROWS + r;
      int bn = e / KK;
      int b = bn >> 11, n = bn & (NPT - 1);
      int j = idx[e];
      const float* pb = pos + (size_t)b * NPT * 3;
      float v;
      if (comp < 3) v = pb[n * 3 + comp];
      else          v = pb[j * 3 + comp - 3] - pb[n * 3 + comp - 3];
      es[i] = v;
    }
    __syncthreads();
    #pragma unroll
    for (int i = 0; i < 20; ++i) {
      int row = (t >> 5) + 8 * i;
      float a = b1a, bvl = b1b;
      #pragma unroll
      for (int d = 0; d < 6; ++d) {
        float ev = es[row * 6 + d];
        a += ev * w1a[d];
        bvl += ev * w1b[d];
      }
      a = a * s1a + sh1a;   a = a > 0.f ? a : 0.f;
      bvl = bvl * s1b + sh1b; bvl = bvl > 0.f ? bvl : 0.f;
      half2_t hh; hh[0] = (_Float16)a; hh[1] = (_Float16)bvl;
      hp[row * 32 + jp2] = hh;
    }
    __syncthreads();
    float acc[20][4];
    #pragma unroll
    for (int r = 0; r < 20; ++r) { acc[r][0] = 0.f; acc[r][1] = 0.f; acc[r][2] = 0.f; acc[r][3] = 0.f; }
    int hbase = rg * 20 * 32;
    #pragma unroll
    for (int step = 0; step < 8; ++step) {
      half8_t wv[4];
      #pragma unroll
      for (int p = 0; p < 4; ++p)
        wv[p] = *(const half8_t*)&w2p[(step * 4 + p) * C2 + c0];
      #pragma unroll
      for (int r = 0; r < 20; ++r) {
        half8_t hv = *(const half8_t*)&hp[hbase + r * 32 + step * 4];
        #pragma unroll
        for (int p = 0; p < 4; ++p) {
          half2_t hpair; hpair[0] = hv[2 * p]; hpair[1] = hv[2 * p + 1];
          #pragma unroll
          for (int k = 0; k < 4; ++k) {
            half2_t wpair; wpair[0] = wv[p][2 * k]; wpair[1] = wv[p][2 * k + 1];
            acc[r][k] = fdot2f(hpair, wpair, acc[r][k]);
          }
        }
      }
    }
    float sm[4] = {0, 0, 0, 0}, sq[4] = {0, 0, 0, 0};
    float mx[4] = {-FLT_MAX, -FLT_MAX, -FLT_MAX, -FLT_MAX};
    float mn[4] = {FLT_MAX, FLT_MAX, FLT_MAX, FLT_MAX};
    #pragma unroll
    for (int r = 0; r < 20; ++r) {
      float a0 = acc[r][0] + b2q.x;
      float a1 = acc[r][1] + b2q.y;
      float a2 = acc[r][2] + b2q.z;
      float a3 = acc[r][3] + b2q.w;
      sm[0] += a0; sq[0] += a0 * a0; mx[0] = fmaxf(mx[0], a0); mn[0] = fminf(mn[0], a0);
      sm[1] += a1; sq[1] += a1 * a1; mx[1] = fmaxf(mx[1], a1); mn[1] = fminf(mn[1], a1);
      sm[2] += a2; sq[2] += a2 * a2; mx[2] = fmaxf(mx[2], a2); mn[2] = fminf(mn[2], a2);
      sm[3] += a3; sq[3] += a3 * a3; mx[3] = fmaxf(mx[3], a3); mn[3] = fminf(mn[3], a3);
    }
    #pragma unroll
    for (int k = 0; k < 4; ++k) { accs[k] += sm[k]; accq[k] += sq[k]; }
    int node = tile * 8 + rg;
    __half2* dst = &am[(size_t)node * C2 + c0];
    dst[0] = __floats2half2_rn(mx[0], mn[0]);
    dst[1] = __floats2half2_rn(mx[1], mn[1]);
    dst[2] = __floats2half2_rn(mx[2], mn[2]);
    dst[3] = __floats2half2_rn(mx[3], mn[3]);
    __syncthreads();
  }
  float* base = part + ((size_t)blockIdx.x * 8 + rg) * 256;
  #pragma unroll
  for (int k = 0; k < 4; ++k) {
    base[c0 + k] = accs[k];
    base[128 + c0 + k] = accq[k];
  }
}

// ---------------- BN2 finalize: reduce f32 partials in f64, one block per channel ----------------
__global__ __launch_bounds__(256) void finalize2_kernel(const float* __restrict__ part,
                                 const float* __restrict__ g2w, const float* __restrict__ be2,
                                 float* __restrict__ scale2, float* __restrict__ shift2) {
  int c = blockIdx.x;   // 128
  int t = threadIdx.x;  // 256
  double s = 0, q = 0;
  for (int i = t; i < N_E2_PART; i += 256) {
    s += (double)part[(size_t)i * 256 + c];
    q += (double)part[(size_t)i * 256 + 128 + c];
  }
  __shared__ double shs[256], shq[256];
  shs[t] = s; shq[t] = q; __syncthreads();
  for (int off = 128; off > 0; off >>= 1) {
    if (t < off) { shs[t] += shs[t + off]; shq[t] += shq[t + off]; }
    __syncthreads();
  }
  if (t == 0) {
    double mean = shs[0] / R1d;
    double var = shq[0] / R1d - mean * mean;
    double sc = (double)g2w[c] / sqrt(var + 1e-5);
    scale2[c] = (float)sc;
    shift2[c] = (float)((double)be2[c] - mean * sc);
  }
}

// node value on the fly: relu(scale * (scale>=0 ? max : min) + shift)
static __device__ __forceinline__ float node_val(__half2 h2, float s, float sh) {
  float A = __low2float(h2), N = __high2float(h2);
  float v = (s >= 0.f ? A : N) * s + sh;
  return v > 0.f ? v : 0.f;
}

// ---------------- Gram partials: BN2 applied on the fly; private 128x128 partial + colsum ----------------
__global__ __launch_bounds__(256) void gram_part_kernel(const __half2* __restrict__ am,
                                                        const float* __restrict__ scale2, const float* __restrict__ shift2,
                                                        float* __restrict__ part) {
  __shared__ float tile[64 * C2];  // 32 KiB
  __shared__ float s_s[C2], s_h[C2];
  int t = threadIdx.x;
  if (t < C2) { s_s[t] = scale2[t]; s_h[t] = shift2[t]; }
  __syncthreads();
  int i = t & 127, jh = t >> 7;
  float acc[64];
  #pragma unroll
  for (int u = 0; u < 64; ++u) acc[u] = 0.f;
  float csum = 0.f;
  for (int tl = blockIdx.x; tl < NNODE / 64; tl += GRAM_GRID) {
    const __half2* a2 = am + (size_t)tl * 64 * C2;
    #pragma unroll
    for (int q = 0; q < 32; ++q) {
      int e = q * 256 + t;
      int c = e & 127;
      tile[e] = node_val(a2[e], s_s[c], s_h[c]);
    }
    __syncthreads();
    #pragma unroll 4
    for (int r = 0; r < 64; ++r) {
      float xi = tile[r * C2 + i];
      const float4* row4 = (const float4*)&tile[r * C2 + jh * 64];
      #pragma unroll
      for (int u4 = 0; u4 < 16; ++u4) {
        float4 v = row4[u4];
        acc[u4 * 4 + 0] += xi * v.x;
        acc[u4 * 4 + 1] += xi * v.y;
        acc[u4 * 4 + 2] += xi * v.z;
        acc[u4 * 4 + 3] += xi * v.w;
      }
    }
    if (t < 128) {
      #pragma unroll 8
      for (int r = 0; r < 64; ++r) csum += tile[r * C2 + t];
    }
    __syncthreads();
  }
  float* pb = part + (size_t)blockIdx.x * GRAM_ELEMS;
  float4* pout = (float4*)(pb + (size_t)i * C2 + jh * 64);
  #pragma unroll
  for (int u4 = 0; u4 < 16; ++u4)
    pout[u4] = make_float4(acc[u4 * 4], acc[u4 * 4 + 1], acc[u4 * 4 + 2], acc[u4 * 4 + 3]);
  if (t < 128) pb[C2 * C2 + t] = csum;
}

// ---------------- Gram reduce: sum partials -> f64 G2 + nodesum ----------------
__global__ __launch_bounds__(256) void gram_reduce_kernel(const float* __restrict__ part,
                                                          double* __restrict__ G2, double* __restrict__ nodesum) {
  int e = blockIdx.x * 256 + threadIdx.x;
  if (e >= GRAM_ELEMS) return;
  double s = 0;
  for (int p = 0; p < GRAM_GRID; ++p) s += (double)part[(size_t)p * GRAM_ELEMS + e];
  if (e < C2 * C2) G2[e] = s;
  else nodesum[e - C2 * C2] = s;
}

// ---------------- BN3 coeffs from Gram ----------------
__global__ __launch_bounds__(128) void finalize3_kernel(const double* __restrict__ G2, const double* __restrict__ nodesum,
    const float* __restrict__ W3, const float* __restrict__ b3,
    const float* __restrict__ g3, const float* __restrict__ be3,
    float* __restrict__ scale3, float* __restrict__ shift3) {
  int c = blockIdx.x;   // 1024 channels
  int t = threadIdx.x;  // 128
  __shared__ double wsh[128];
  __shared__ double sh[128];
  double w = W3[(size_t)t * EMB + c];
  wsh[t] = w;
  __syncthreads();
  double rowdot = 0;
  for (int j = 0; j < 128; ++j) rowdot += G2[(size_t)j * C2 + t] * wsh[j];
  sh[t] = w * rowdot;
  __syncthreads();
  for (int off = 64; off > 0; off >>= 1) { if (t < off) sh[t] += sh[t + off]; __syncthreads(); }
  double quad = sh[0];
  __syncthreads();
  sh[t] = w * nodesum[t];
  __syncthreads();
  for (int off = 64; off > 0; off >>= 1) { if (t < off) sh[t] += sh[t + off]; __syncthreads(); }
  if (t == 0) {
    double wm = sh[0];
    double bb = b3[c];
    double mean = wm / R3d + bb;
    double E2 = (quad + 2.0 * bb * wm) / R3d + bb * bb;
    double var = E2 - mean * mean;
    double sc = (double)g3[c] / sqrt(var + 1e-5);
    scale3[c] = (float)sc;
    shift3[c] = (float)((double)be3[c] - mean * sc);
  }
}

// ---------------- linear1 apply v3: fp16 node tile + packed W3 + fdot2 ----------------
__global__ __launch_bounds__(256) void apply3pool_kernel(const __half2* __restrict__ am,
    const float* __restrict__ scale2, const float* __restrict__ shift2,
    const half2_t* __restrict__ w3h, const float* __restrict__ b3,
    const float* __restrict__ scale3, const float* __restrict__ shift3,
    float* __restrict__ pp, float* __restrict__ ps) {
  __shared__ half2_t tileh[32 * 64];  // 8 KiB: (row, kp) packed pairs along K
  __shared__ float s_s[C2], s_h[C2];
  int rt = blockIdx.x;  // 1024 row tiles of 32 rows
  int ct = blockIdx.y;  // 2 column halves
  int t = threadIdx.x;
  if (t < C2) { s_s[t] = scale2[t]; s_h[t] = shift2[t]; }
  __syncthreads();
  // stage node tile: 32 rows x 64 kp
  const __half2* a2 = am + (size_t)rt * 32 * C2;
  #pragma unroll
  for (int q = 0; q < 8; ++q) {
    int e = q * 256 + t;           // pair index: row = e>>6, kp = e&63
    int row = e >> 6, kp = e & 63;
    __half2 h0 = a2[row * C2 + 2 * kp];
    __half2 h1 = a2[row * C2 + 2 * kp + 1];
    float v0 = node_val(h0, s_s[2 * kp], s_h[2 * kp]);
    float v1 = node_val(h1, s_s[2 * kp + 1], s_h[2 * kp + 1]);
    half2_t hh; hh[0] = (_Float16)v0; hh[1] = (_Float16)v1;
    tileh[e] = hh;
  }
  __syncthreads();
  int c0 = ct * 512 + t;
  int c1 = c0 + 256;
  float a0[32], a1[32];
  #pragma unroll
  for (int r = 0; r < 32; ++r) { a0[r] = 0.f; a1[r] = 0.f; }
  #pragma unroll 4
  for (int kq = 0; kq < 16; ++kq) {   // kp quads
    half2_t w0a = w3h[(size_t)(kq * 4 + 0) * EMB + c0];
    half2_t w1a = w3h[(size_t)(kq * 4 + 1) * EMB + c0];
    half2_t w2a = w3h[(size_t)(kq * 4 + 2) * EMB + c0];
    half2_t w3a = w3h[(size_t)(kq * 4 + 3) * EMB + c0];
    half2_t w0b = w3h[(size_t)(kq * 4 + 0) * EMB + c1];
    half2_t w1b = w3h[(size_t)(kq * 4 + 1) * EMB + c1];
    half2_t w2b = w3h[(size_t)(kq * 4 + 2) * EMB + c1];
    half2_t w3b = w3h[(size_t)(kq * 4 + 3) * EMB + c1];
    #pragma unroll
    for (int r = 0; r < 32; ++r) {
      half8_t hv = *(const half8_t*)&tileh[r * 64 + kq * 4];
      half2_t p0; p0[0] = hv[0]; p0[1] = hv[1];
      half2_t p1; p1[0] = hv[2]; p1[1] = hv[3];
      half2_t p2; p2[0] = hv[4]; p2[1] = hv[5];
      half2_t p3; p3[0] = hv[6]; p3[1] = hv[7];
      a0[r] = fdot2f(p0, w0a, a0[r]); a0[r] = fdot2f(p1, w1a, a0[r]);
      a0[r] = fdot2f(p2, w2a, a0[r]); a0[r] = fdot2f(p3, w3a, a0[r]);
      a1[r] = fdot2f(p0, w0b, a1[r]); a1[r] = fdot2f(p1, w1b, a1[r]);
      a1[r] = fdot2f(p2, w2b, a1[r]); a1[r] = fdot2f(p3, w3b, a1[r]);
    }
  }
  float b30 = b3[c0], s30 = scale3[c0], sh30 = shift3[c0];
  float b31 = b3[c1], s31 = scale3[c1], sh31 = shift3[c1];
  float mx0 = 0.f, sm0 = 0.f, mx1 = 0.f, sm1 = 0.f;
  #pragma unroll
  for (int r = 0; r < 32; ++r) {
    float x0 = (a0[r] + b30) * s30 + sh30; x0 = x0 > 0.f ? x0 : 0.f; mx0 = mx0 > x0 ? mx0 : x0; sm0 += x0;
    float x1 = (a1[r] + b31) * s31 + sh31; x1 = x1 > 0.f ? x1 : 0.f; mx1 = mx1 > x1 ? mx1 : x1; sm1 += x1;
  }
  float* ppb = pp + (size_t)rt * EMB;
  float* psb = ps + (size_t)rt * EMB;
  ppb[c0] = mx0; psb[c0] = sm0;
  ppb[c1] = mx1; psb[c1] = sm1;
}

// ---------------- pool reduce: per (b,c) max/sum over 64 row tiles ----------------
__global__ __launch_bounds__(256) void poolreduce_kernel(const float* __restrict__ pp, const float* __restrict__ ps,
                                                         float* __restrict__ pmaxo, float* __restrict__ psumo) {
  int e = blockIdx.x * 256 + threadIdx.x;  // e = b*1024 + c, grid 64
  int b = e >> 10, c = e & 1023;
  const float* bp = pp + ((size_t)b * 64) * EMB + c;
  const float* bs = ps + ((size_t)b * 64) * EMB + c;
  float mx = 0.f, sm = 0.f;
  #pragma unroll 8
  for (int tl = 0; tl < 64; ++tl) {
    float v = bp[(size_t)tl * EMB];
    float s = bs[(size_t)tl * EMB];
    mx = mx > v ? mx : v;
    sm += s;
  }
  pmaxo[e] = mx;
  psumo[e] = sm;
}

// ---------------- final linear: pooled[16,2048] @ W4 + b4 -> out[16,7] ----------------
__global__ __launch_bounds__(64) void final_kernel(const float* __restrict__ pmax, const float* __restrict__ psum,
    const float* __restrict__ W4, const float* __restrict__ b4, float* __restrict__ out) {
  int b = blockIdx.x, t = threadIdx.x;
  #pragma unroll
  for (int o = 0; o < OUT; ++o) {
    float acc = 0.f;
    for (int tt = t; tt < 2 * EMB; tt += 64) {
      float p = (tt < EMB) ? pmax[(size_t)b * EMB + tt]
                           : psum[(size_t)b * EMB + tt - EMB] * (1.0f / (float)NPT);
      acc += p * W4[(size_t)tt * OUT + o];
    }
    #pragma unroll
    for (int off = 32; off > 0; off >>= 1) acc += __shfl_down(acc, off);
    if (t == 0) out[b * OUT + o] = acc + b4[o];
  }
}

extern "C" void kernel_launch(void* const* d_in, const int* in_sizes, int n_in,
                              void* d_out, int out_size, void* d_ws, size_t ws_size,
                              hipStream_t stream) {
  const float* pos = (const float*)d_in[0];
  const float* W1 = (const float*)d_in[1];  const float* b1 = (const float*)d_in[2];
  const float* g1 = (const float*)d_in[3];  const float* be1 = (const float*)d_in[4];
  const float* W2 = (const float*)d_in[5];  const float* b2 = (const float*)d_in[6];
  const float* g2 = (const float*)d_in[7];  const float* be2 = (const float*)d_in[8];
  const float* W3 = (const float*)d_in[9];  const float* b3 = (const float*)d_in[10];
  const float* g3 = (const float*)d_in[11]; const float* be3 = (const float*)d_in[12];
  const float* W4 = (const float*)d_in[13]; const float* b4 = (const float*)d_in[14];
  float* out = (float*)d_out;

  // ---- workspace layout, total ~25.9 MiB (25.6 proven safe in rounds 4-7) ----
  char* ws = (char*)d_ws;
  unsigned short* idx = (unsigned short*)ws;               // NEDGE u16 = 1.25 MiB
  __half2* am = (__half2*)(ws + (size_t)NEDGE * 2);        // NNODE*C2 half2 = 16 MiB
  char* smallbase = (char*)(am + (size_t)NNODE * C2);

  double* dstats  = (double*)smallbase;           // 32 (27 used)
  double* G2      = dstats + 32;                  // 16384
  double* nodesum = G2 + 16384;                   // 128
  float* scale1 = (float*)(nodesum + 128);
  float* shift1 = scale1 + C1;
  float* scale2 = shift1 + C1;
  float* shift2 = scale2 + C2;
  float* scale3 = shift2 + C2;
  float* shift3 = scale3 + EMB;
  float* pooledmax = shift3 + EMB;                // 16*1024
  float* pooledsum = pooledmax + NB * EMB;        // 16*1024
  half2_t* w3h = (half2_t*)(pooledsum + NB * EMB);// 64*1024 half2 = 256 KiB
  char* scratch = (char*)(w3h + 64 * EMB);
  // lifetime-disjoint overlays on one ~8.45 MiB slab:
  float* eg_part   = (float*)scratch;             // 8192*256*4  = 8.00 MiB (edge2 -> finalize2)
  float* gram_part = (float*)scratch;             // 128*16512*4 = 8.06 MiB (gram_part -> gram_reduce)
  float* pp        = (float*)scratch;             // 1024*1024*4 = 4 MiB    (apply3pool -> poolreduce)
  float* psb       = pp + (size_t)1024 * EMB;     // 4 MiB

  hipMemsetAsync(dstats, 0, 32 * sizeof(double), stream);

  knn_kernel<<<NB * NPT / 4, 256, 0, stream>>>(pos, idx);
  packw3_kernel<<<64 * EMB / 256, 256, 0, stream>>>(W3, w3h);
  statse_kernel<<<512, 256, 0, stream>>>(pos, idx, dstats);
  finalize1_kernel<<<1, 64, 0, stream>>>(dstats, W1, b1, g1, be1, scale1, shift1);
  edge2_kernel<<<E2_BLOCKS, 256, 0, stream>>>(pos, idx, W1, b1, scale1, shift1, W2, b2, am, eg_part);
  finalize2_kernel<<<C2, 256, 0, stream>>>(eg_part, g2, be2, scale2, shift2);
  gram_part_kernel<<<GRAM_GRID, 256, 0, stream>>>(am, scale2, shift2, gram_part);
  gram_reduce_kernel<<<(GRAM_ELEMS + 255) / 256, 256, 0, stream>>>(gram_part, G2, nodesum);
  finalize3_kernel<<<EMB, 128, 0, stream>>>(G2, nodesum, W3, b3, g3, be3, scale3, shift3);
  apply3pool_kernel<<<dim3(1024, 2), 256, 0, stream>>>(am, scale2, shift2, w3h, b3, scale3, shift3, pp, psb);
  poolreduce_kernel<<<NB * EMB / 256, 256, 0, stream>>>(pp, psb, pooledmax, pooledsum);
  final_kernel<<<NB, 64, 0, stream>>>(pooledmax, pooledsum, W4, b4, out);
}

// Round 9
// 699.584 us; speedup vs baseline: 1.2854x; 1.0187x over previous
//
#include <hip/hip_runtime.h>
#include <hip/hip_fp16.h>
#include <float.h>

// ---- fixed problem shape ----
constexpr int NB  = 16;     // batch (clouds)
constexpr int NPT = 2048;   // points per cloud
constexpr int KK  = 20;     // kNN
constexpr int NEDGE = NB * NPT * KK;       // 655360
constexpr int C1 = 64, C2 = 128, EMB = 1024, OUT = 7;
constexpr int NNODE = NB * NPT;            // 32768
constexpr int E2_BLOCKS = 1024;            // edge2 grid (4 tiles each)
constexpr int N_E2_PART = 8192;            // edge2 stat partials (1024 blocks x 8 row-groups)
constexpr int GRAM_GRID = 128;
constexpr int GRAM_ELEMS = C2 * C2 + C2;   // 16512 (Gram + colsum)
__device__ constexpr double R1d = (double)NEDGE;       // BN1/BN2 row count
__device__ constexpr double R3d = (double)(NB * NPT);  // BN3 row count

using half2_t = _Float16 __attribute__((ext_vector_type(2)));
using half8_t = _Float16 __attribute__((ext_vector_type(8)));

static __device__ __forceinline__ float fdot2f(half2_t a, half2_t b, float c) {
  return __builtin_amdgcn_fdot2(a, b, c, false);
}

static __device__ __forceinline__ unsigned long long ullmin2(unsigned long long a, unsigned long long b) {
  return a < b ? a : b;
}

// ---------------- kNN v4: register-resident keys (launch_bounds(256,2) -> ~256 VGPR cap)
// Round-4 lesson: runtime-indexed key[] -> scratch (525 MB spills). Round-8 lesson:
// default occupancy target capped VGPRs at 56 -> compiler rematerialized keys from
// L1 every round (9400 inst/wave). The (256,2) bound lifts the cap so key[32] (64
// VGPRs) stays resident. Threshold via wraparound subtraction: d = key - T wraps
// consumed keys (< T) to huge values; winner = min(d) + T. Exact (keys distinct).
__global__ __launch_bounds__(256, 2) void knn_kernel(const float* __restrict__ pos, unsigned short* __restrict__ idxo) {
  int t = threadIdx.x;
  int lane = t & 63, w = t >> 6;
  int bn = blockIdx.x * 4 + w;            // 8192 blocks x 4 waves = 32768 queries
  int b = bn >> 11, n = bn & (NPT - 1);
  const float* pb = pos + (size_t)b * NPT * 3;
  float xn = pb[n * 3], yn = pb[n * 3 + 1], zn = pb[n * 3 + 2];
  float sqn = xn * xn + yn * yn + zn * zn;

  unsigned long long key[32];
  #pragma unroll
  for (int i = 0; i < 32; ++i) {
    int m = i * 64 + lane;
    float xm = pb[m * 3], ym = pb[m * 3 + 1], zm = pb[m * 3 + 2];
    float sqm = xm * xm + ym * ym + zm * zm;
    float dt = xn * xm + yn * ym + zn * zm;
    float d = sqn + sqm - 2.0f * dt;
    unsigned ub = __float_as_uint(d);
    ub = (ub & 0x80000000u) ? ~ub : (ub | 0x80000000u);  // order-preserving map
    key[i] = ((unsigned long long)ub << 32) | (unsigned long long)(unsigned)m;
  }

  unsigned long long T = 0;
  int myidx = 0;
  for (int r = 0; r < KK; ++r) {
    // d = key - T: consumed keys (< T) wrap to the top of the u64 range.
    unsigned long long t0[16];
    #pragma unroll
    for (int i = 0; i < 16; ++i)
      t0[i] = ullmin2(key[2 * i] - T, key[2 * i + 1] - T);
    #pragma unroll
    for (int s = 8; s > 0; s >>= 1)
      #pragma unroll
      for (int i = 0; i < 8; ++i)
        if (i < s) t0[i] = ullmin2(t0[i], t0[i + s]);
    unsigned long long best = t0[0];
    #pragma unroll
    for (int off = 32; off > 0; off >>= 1) {
      unsigned long long o = (unsigned long long)__shfl_xor((long long)best, off, 64);
      best = ullmin2(best, o);
    }
    unsigned long long winner = best + T;
    if (lane == r) myidx = (int)(unsigned)(winner & 0xffffffffull);
    T = winner + 1;
  }
  if (lane < KK) idxo[(size_t)bn * KK + lane] = (unsigned short)myidx;
}

// ---------------- edge-feature first/second moments (6 + 21 doubles) ----------------
__global__ __launch_bounds__(256) void statse_kernel(const float* __restrict__ pos, const unsigned short* __restrict__ idx,
                                                     double* __restrict__ dstats) {
  float acc[27];
  #pragma unroll
  for (int i = 0; i < 27; ++i) acc[i] = 0.f;
  int t = threadIdx.x;
  for (int e = blockIdx.x * 256 + t; e < NEDGE; e += gridDim.x * 256) {
    int bn = e / KK;
    int b = bn >> 11, n = bn & (NPT - 1);
    int j = idx[e];
    const float* pb = pos + (size_t)b * NPT * 3;
    float f[6];
    f[0] = pb[n * 3]; f[1] = pb[n * 3 + 1]; f[2] = pb[n * 3 + 2];
    f[3] = pb[j * 3] - f[0]; f[4] = pb[j * 3 + 1] - f[1]; f[5] = pb[j * 3 + 2] - f[2];
    int p = 6;
    #pragma unroll
    for (int d = 0; d < 6; ++d) acc[d] += f[d];
    #pragma unroll
    for (int d = 0; d < 6; ++d)
      #pragma unroll
      for (int q = d; q < 6; ++q) { acc[p] += f[d] * f[q]; ++p; }
  }
  __shared__ float sred[4][27];
  int lane = t & 63, w = t >> 6;
  #pragma unroll
  for (int c = 0; c < 27; ++c) {
    float v = acc[c];
    #pragma unroll
    for (int off = 32; off > 0; off >>= 1) v += __shfl_down(v, off);
    if (lane == 0) sred[w][c] = v;
  }
  __syncthreads();
  if (t < 27) {
    double s = (double)sred[0][t] + (double)sred[1][t] + (double)sred[2][t] + (double)sred[3][t];
    atomicAdd(&dstats[t], s);
  }
}

// ---------------- BN1 coeffs from moments ----------------
__global__ void finalize1_kernel(const double* __restrict__ dstats, const float* __restrict__ W1,
                                 const float* __restrict__ b1, const float* __restrict__ g1,
                                 const float* __restrict__ be1, float* __restrict__ scale1,
                                 float* __restrict__ shift1) {
  int c = threadIdx.x;  // 64
  double m1[6], M2[6][6];
  for (int d = 0; d < 6; ++d) m1[d] = dstats[d];
  int p = 6;
  for (int d = 0; d < 6; ++d)
    for (int q = d; q < 6; ++q) { M2[d][q] = dstats[p]; M2[q][d] = dstats[p]; ++p; }
  double w[6];
  for (int d = 0; d < 6; ++d) w[d] = W1[d * C1 + c];
  double wm = 0, quad = 0;
  for (int d = 0; d < 6; ++d) wm += w[d] * m1[d];
  for (int d = 0; d < 6; ++d) {
    double s = 0;
    for (int q = 0; q < 6; ++q) s += M2[d][q] * w[q];
    quad += w[d] * s;
  }
  double bb = b1[c];
  double mean = wm / R1d + bb;
  double E2 = (quad + 2.0 * bb * wm) / R1d + bb * bb;
  double var = E2 - mean * mean;
  double sc = (double)g1[c] / sqrt(var + 1e-5);
  scale1[c] = (float)sc;
  shift1[c] = (float)((double)be1[c] - mean * sc);
}

// ---------------- W3 -> half2 K-paired pack: w3h[kp*EMB + c] = (W3[2kp][c], W3[2kp+1][c]) ----------------
__global__ __launch_bounds__(256) void packw3_kernel(const float* __restrict__ W3, half2_t* __restrict__ w3h) {
  int e = blockIdx.x * 256 + threadIdx.x;   // 65536 = 64 kp x 1024 c
  int kp = e >> 10, c = e & 1023;
  float w0 = W3[(size_t)(2 * kp) * EMB + c];
  float w1 = W3[(size_t)(2 * kp + 1) * EMB + c];
  half2_t h; h[0] = (_Float16)w0; h[1] = (_Float16)w1;
  w3h[e] = h;
}

// ---------------- fused edge pass v3: fp16 LDS + v_dot2, 4 blocks/CU ----------------
__global__ __launch_bounds__(256) void edge2_kernel(const float* __restrict__ pos, const unsigned short* __restrict__ idx,
    const float* __restrict__ W1, const float* __restrict__ b1,
    const float* __restrict__ scale1, const float* __restrict__ shift1,
    const float* __restrict__ W2, const float* __restrict__ b2,
    __half2* __restrict__ am, float* __restrict__ part) {
  constexpr int TROWS = 160;              // 8 nodes x 20 edges
  __shared__ half2_t w2p[32 * C2];        // 16 KiB  (pair jp, col c) = (W2[2jp][c], W2[2jp+1][c])
  __shared__ half2_t hp[TROWS * 32];      // 20 KiB  (row, pair jp)
  __shared__ float es[TROWS * 6];         // 3.75 KiB
  int t = threadIdx.x;

  for (int i = t; i < 32 * C2; i += 256) {
    int jp = i >> 7, c = i & 127;
    float w0 = W2[(2 * jp) * C2 + c], w1 = W2[(2 * jp + 1) * C2 + c];
    half2_t hw; hw[0] = (_Float16)w0; hw[1] = (_Float16)w1;
    w2p[i] = hw;
  }
  int jp2 = t & 31;
  float w1a[6], w1b[6];
  #pragma unroll
  for (int d = 0; d < 6; ++d) {
    w1a[d] = W1[d * C1 + 2 * jp2];
    w1b[d] = W1[d * C1 + 2 * jp2 + 1];
  }
  float b1a = b1[2 * jp2], s1a = scale1[2 * jp2], sh1a = shift1[2 * jp2];
  float b1b = b1[2 * jp2 + 1], s1b = scale1[2 * jp2 + 1], sh1b = shift1[2 * jp2 + 1];
  int cq = t & 31, rg = t >> 5;
  int c0 = cq * 4;
  float4 b2q = *(const float4*)&b2[c0];
  float accs[4] = {0, 0, 0, 0}, accq[4] = {0, 0, 0, 0};

  for (int tile = blockIdx.x; tile < NNODE / 8; tile += E2_BLOCKS) {
    for (int i = t; i < TROWS * 6; i += 256) {
      int r = i / 6, comp = i - r * 6;
      int e = tile * TROWS + r;
      int bn = e / KK;
      int b = bn >> 11, n = bn & (NPT - 1);
      int j = idx[e];
      const float* pb = pos + (size_t)b * NPT * 3;
      float v;
      if (comp < 3) v = pb[n * 3 + comp];
      else          v = pb[j * 3 + comp - 3] - pb[n * 3 + comp - 3];
      es[i] = v;
    }
    __syncthreads();
    #pragma unroll
    for (int i = 0; i < 20; ++i) {
      int row = (t >> 5) + 8 * i;
      float a = b1a, bvl = b1b;
      #pragma unroll
      for (int d = 0; d < 6; ++d) {
        float ev = es[row * 6 + d];
        a += ev * w1a[d];
        bvl += ev * w1b[d];
      }
      a = a * s1a + sh1a;   a = a > 0.f ? a : 0.f;
      bvl = bvl * s1b + sh1b; bvl = bvl > 0.f ? bvl : 0.f;
      half2_t hh; hh[0] = (_Float16)a; hh[1] = (_Float16)bvl;
      hp[row * 32 + jp2] = hh;
    }
    __syncthreads();
    float acc[20][4];
    #pragma unroll
    for (int r = 0; r < 20; ++r) { acc[r][0] = 0.f; acc[r][1] = 0.f; acc[r][2] = 0.f; acc[r][3] = 0.f; }
    int hbase = rg * 20 * 32;
    #pragma unroll
    for (int step = 0; step < 8; ++step) {
      half8_t wv[4];
      #pragma unroll
      for (int p = 0; p < 4; ++p)
        wv[p] = *(const half8_t*)&w2p[(step * 4 + p) * C2 + c0];
      #pragma unroll
      for (int r = 0; r < 20; ++r) {
        half8_t hv = *(const half8_t*)&hp[hbase + r * 32 + step * 4];
        #pragma unroll
        for (int p = 0; p < 4; ++p) {
          half2_t hpair; hpair[0] = hv[2 * p]; hpair[1] = hv[2 * p + 1];
          #pragma unroll
          for (int k = 0; k < 4; ++k) {
            half2_t wpair; wpair[0] = wv[p][2 * k]; wpair[1] = wv[p][2 * k + 1];
            acc[r][k] = fdot2f(hpair, wpair, acc[r][k]);
          }
        }
      }
    }
    float sm[4] = {0, 0, 0, 0}, sq[4] = {0, 0, 0, 0};
    float mx[4] = {-FLT_MAX, -FLT_MAX, -FLT_MAX, -FLT_MAX};
    float mn[4] = {FLT_MAX, FLT_MAX, FLT_MAX, FLT_MAX};
    #pragma unroll
    for (int r = 0; r < 20; ++r) {
      float a0 = acc[r][0] + b2q.x;
      float a1 = acc[r][1] + b2q.y;
      float a2 = acc[r][2] + b2q.z;
      float a3 = acc[r][3] + b2q.w;
      sm[0] += a0; sq[0] += a0 * a0; mx[0] = fmaxf(mx[0], a0); mn[0] = fminf(mn[0], a0);
      sm[1] += a1; sq[1] += a1 * a1; mx[1] = fmaxf(mx[1], a1); mn[1] = fminf(mn[1], a1);
      sm[2] += a2; sq[2] += a2 * a2; mx[2] = fmaxf(mx[2], a2); mn[2] = fminf(mn[2], a2);
      sm[3] += a3; sq[3] += a3 * a3; mx[3] = fmaxf(mx[3], a3); mn[3] = fminf(mn[3], a3);
    }
    #pragma unroll
    for (int k = 0; k < 4; ++k) { accs[k] += sm[k]; accq[k] += sq[k]; }
    int node = tile * 8 + rg;
    __half2* dst = &am[(size_t)node * C2 + c0];
    dst[0] = __floats2half2_rn(mx[0], mn[0]);
    dst[1] = __floats2half2_rn(mx[1], mn[1]);
    dst[2] = __floats2half2_rn(mx[2], mn[2]);
    dst[3] = __floats2half2_rn(mx[3], mn[3]);
    __syncthreads();
  }
  float* base = part + ((size_t)blockIdx.x * 8 + rg) * 256;
  #pragma unroll
  for (int k = 0; k < 4; ++k) {
    base[c0 + k] = accs[k];
    base[128 + c0 + k] = accq[k];
  }
}

// ---------------- BN2 finalize: reduce f32 partials in f64, one block per channel ----------------
__global__ __launch_bounds__(256) void finalize2_kernel(const float* __restrict__ part,
                                 const float* __restrict__ g2w, const float* __restrict__ be2,
                                 float* __restrict__ scale2, float* __restrict__ shift2) {
  int c = blockIdx.x;   // 128
  int t = threadIdx.x;  // 256
  double s = 0, q = 0;
  for (int i = t; i < N_E2_PART; i += 256) {
    s += (double)part[(size_t)i * 256 + c];
    q += (double)part[(size_t)i * 256 + 128 + c];
  }
  __shared__ double shs[256], shq[256];
  shs[t] = s; shq[t] = q; __syncthreads();
  for (int off = 128; off > 0; off >>= 1) {
    if (t < off) { shs[t] += shs[t + off]; shq[t] += shq[t + off]; }
    __syncthreads();
  }
  if (t == 0) {
    double mean = shs[0] / R1d;
    double var = shq[0] / R1d - mean * mean;
    double sc = (double)g2w[c] / sqrt(var + 1e-5);
    scale2[c] = (float)sc;
    shift2[c] = (float)((double)be2[c] - mean * sc);
  }
}

// node value on the fly: relu(scale * (scale>=0 ? max : min) + shift)
static __device__ __forceinline__ float node_val(__half2 h2, float s, float sh) {
  float A = __low2float(h2), N = __high2float(h2);
  float v = (s >= 0.f ? A : N) * s + sh;
  return v > 0.f ? v : 0.f;
}

// ---------------- Gram partials: BN2 applied on the fly; private 128x128 partial + colsum ----------------
__global__ __launch_bounds__(256) void gram_part_kernel(const __half2* __restrict__ am,
                                                        const float* __restrict__ scale2, const float* __restrict__ shift2,
                                                        float* __restrict__ part) {
  __shared__ float tile[64 * C2];  // 32 KiB
  __shared__ float s_s[C2], s_h[C2];
  int t = threadIdx.x;
  if (t < C2) { s_s[t] = scale2[t]; s_h[t] = shift2[t]; }
  __syncthreads();
  int i = t & 127, jh = t >> 7;
  float acc[64];
  #pragma unroll
  for (int u = 0; u < 64; ++u) acc[u] = 0.f;
  float csum = 0.f;
  for (int tl = blockIdx.x; tl < NNODE / 64; tl += GRAM_GRID) {
    const __half2* a2 = am + (size_t)tl * 64 * C2;
    #pragma unroll
    for (int q = 0; q < 32; ++q) {
      int e = q * 256 + t;
      int c = e & 127;
      tile[e] = node_val(a2[e], s_s[c], s_h[c]);
    }
    __syncthreads();
    #pragma unroll 4
    for (int r = 0; r < 64; ++r) {
      float xi = tile[r * C2 + i];
      const float4* row4 = (const float4*)&tile[r * C2 + jh * 64];
      #pragma unroll
      for (int u4 = 0; u4 < 16; ++u4) {
        float4 v = row4[u4];
        acc[u4 * 4 + 0] += xi * v.x;
        acc[u4 * 4 + 1] += xi * v.y;
        acc[u4 * 4 + 2] += xi * v.z;
        acc[u4 * 4 + 3] += xi * v.w;
      }
    }
    if (t < 128) {
      #pragma unroll 8
      for (int r = 0; r < 64; ++r) csum += tile[r * C2 + t];
    }
    __syncthreads();
  }
  float* pb = part + (size_t)blockIdx.x * GRAM_ELEMS;
  float4* pout = (float4*)(pb + (size_t)i * C2 + jh * 64);
  #pragma unroll
  for (int u4 = 0; u4 < 16; ++u4)
    pout[u4] = make_float4(acc[u4 * 4], acc[u4 * 4 + 1], acc[u4 * 4 + 2], acc[u4 * 4 + 3]);
  if (t < 128) pb[C2 * C2 + t] = csum;
}

// ---------------- Gram reduce: sum partials -> f64 G2 + nodesum ----------------
__global__ __launch_bounds__(256) void gram_reduce_kernel(const float* __restrict__ part,
                                                          double* __restrict__ G2, double* __restrict__ nodesum) {
  int e = blockIdx.x * 256 + threadIdx.x;
  if (e >= GRAM_ELEMS) return;
  double s = 0;
  for (int p = 0; p < GRAM_GRID; ++p) s += (double)part[(size_t)p * GRAM_ELEMS + e];
  if (e < C2 * C2) G2[e] = s;
  else nodesum[e - C2 * C2] = s;
}

// ---------------- BN3 coeffs from Gram ----------------
__global__ __launch_bounds__(128) void finalize3_kernel(const double* __restrict__ G2, const double* __restrict__ nodesum,
    const float* __restrict__ W3, const float* __restrict__ b3,
    const float* __restrict__ g3, const float* __restrict__ be3,
    float* __restrict__ scale3, float* __restrict__ shift3) {
  int c = blockIdx.x;   // 1024 channels
  int t = threadIdx.x;  // 128
  __shared__ double wsh[128];
  __shared__ double sh[128];
  double w = W3[(size_t)t * EMB + c];
  wsh[t] = w;
  __syncthreads();
  double rowdot = 0;
  for (int j = 0; j < 128; ++j) rowdot += G2[(size_t)j * C2 + t] * wsh[j];
  sh[t] = w * rowdot;
  __syncthreads();
  for (int off = 64; off > 0; off >>= 1) { if (t < off) sh[t] += sh[t + off]; __syncthreads(); }
  double quad = sh[0];
  __syncthreads();
  sh[t] = w * nodesum[t];
  __syncthreads();
  for (int off = 64; off > 0; off >>= 1) { if (t < off) sh[t] += sh[t + off]; __syncthreads(); }
  if (t == 0) {
    double wm = sh[0];
    double bb = b3[c];
    double mean = wm / R3d + bb;
    double E2 = (quad + 2.0 * bb * wm) / R3d + bb * bb;
    double var = E2 - mean * mean;
    double sc = (double)g3[c] / sqrt(var + 1e-5);
    scale3[c] = (float)sc;
    shift3[c] = (float)((double)be3[c] - mean * sc);
  }
}

// ---------------- linear1 apply v3: fp16 node tile + packed W3 + fdot2 ----------------
__global__ __launch_bounds__(256) void apply3pool_kernel(const __half2* __restrict__ am,
    const float* __restrict__ scale2, const float* __restrict__ shift2,
    const half2_t* __restrict__ w3h, const float* __restrict__ b3,
    const float* __restrict__ scale3, const float* __restrict__ shift3,
    float* __restrict__ pp, float* __restrict__ ps) {
  __shared__ half2_t tileh[32 * 64];  // 8 KiB: (row, kp) packed pairs along K
  __shared__ float s_s[C2], s_h[C2];
  int rt = blockIdx.x;  // 1024 row tiles of 32 rows
  int ct = blockIdx.y;  // 2 column halves
  int t = threadIdx.x;
  if (t < C2) { s_s[t] = scale2[t]; s_h[t] = shift2[t]; }
  __syncthreads();
  const __half2* a2 = am + (size_t)rt * 32 * C2;
  #pragma unroll
  for (int q = 0; q < 8; ++q) {
    int e = q * 256 + t;           // pair index: row = e>>6, kp = e&63
    int row = e >> 6, kp = e & 63;
    __half2 h0 = a2[row * C2 + 2 * kp];
    __half2 h1 = a2[row * C2 + 2 * kp + 1];
    float v0 = node_val(h0, s_s[2 * kp], s_h[2 * kp]);
    float v1 = node_val(h1, s_s[2 * kp + 1], s_h[2 * kp + 1]);
    half2_t hh; hh[0] = (_Float16)v0; hh[1] = (_Float16)v1;
    tileh[e] = hh;
  }
  __syncthreads();
  int c0 = ct * 512 + t;
  int c1 = c0 + 256;
  float a0[32], a1[32];
  #pragma unroll
  for (int r = 0; r < 32; ++r) { a0[r] = 0.f; a1[r] = 0.f; }
  #pragma unroll 4
  for (int kq = 0; kq < 16; ++kq) {   // kp quads
    half2_t w0a = w3h[(size_t)(kq * 4 + 0) * EMB + c0];
    half2_t w1a = w3h[(size_t)(kq * 4 + 1) * EMB + c0];
    half2_t w2a = w3h[(size_t)(kq * 4 + 2) * EMB + c0];
    half2_t w3a = w3h[(size_t)(kq * 4 + 3) * EMB + c0];
    half2_t w0b = w3h[(size_t)(kq * 4 + 0) * EMB + c1];
    half2_t w1b = w3h[(size_t)(kq * 4 + 1) * EMB + c1];
    half2_t w2b = w3h[(size_t)(kq * 4 + 2) * EMB + c1];
    half2_t w3b = w3h[(size_t)(kq * 4 + 3) * EMB + c1];
    #pragma unroll
    for (int r = 0; r < 32; ++r) {
      half8_t hv = *(const half8_t*)&tileh[r * 64 + kq * 4];
      half2_t p0; p0[0] = hv[0]; p0[1] = hv[1];
      half2_t p1; p1[0] = hv[2]; p1[1] = hv[3];
      half2_t p2; p2[0] = hv[4]; p2[1] = hv[5];
      half2_t p3; p3[0] = hv[6]; p3[1] = hv[7];
      a0[r] = fdot2f(p0, w0a, a0[r]); a0[r] = fdot2f(p1, w1a, a0[r]);
      a0[r] = fdot2f(p2, w2a, a0[r]); a0[r] = fdot2f(p3, w3a, a0[r]);
      a1[r] = fdot2f(p0, w0b, a1[r]); a1[r] = fdot2f(p1, w1b, a1[r]);
      a1[r] = fdot2f(p2, w2b, a1[r]); a1[r] = fdot2f(p3, w3b, a1[r]);
    }
  }
  float b30 = b3[c0], s30 = scale3[c0], sh30 = shift3[c0];
  float b31 = b3[c1], s31 = scale3[c1], sh31 = shift3[c1];
  float mx0 = 0.f, sm0 = 0.f, mx1 = 0.f, sm1 = 0.f;
  #pragma unroll
  for (int r = 0; r < 32; ++r) {
    float x0 = (a0[r] + b30) * s30 + sh30; x0 = x0 > 0.f ? x0 : 0.f; mx0 = mx0 > x0 ? mx0 : x0; sm0 += x0;
    float x1 = (a1[r] + b31) * s31 + sh31; x1 = x1 > 0.f ? x1 : 0.f; mx1 = mx1 > x1 ? mx1 : x1; sm1 += x1;
  }
  float* ppb = pp + (size_t)rt * EMB;
  float* psb = ps + (size_t)rt * EMB;
  ppb[c0] = mx0; psb[c0] = sm0;
  ppb[c1] = mx1; psb[c1] = sm1;
}

// ---------------- pool reduce: per (b,c) max/sum over 64 row tiles ----------------
__global__ __launch_bounds__(256) void poolreduce_kernel(const float* __restrict__ pp, const float* __restrict__ ps,
                                                         float* __restrict__ pmaxo, float* __restrict__ psumo) {
  int e = blockIdx.x * 256 + threadIdx.x;  // e = b*1024 + c, grid 64
  int b = e >> 10, c = e & 1023;
  const float* bp = pp + ((size_t)b * 64) * EMB + c;
  const float* bs = ps + ((size_t)b * 64) * EMB + c;
  float mx = 0.f, sm = 0.f;
  #pragma unroll 8
  for (int tl = 0; tl < 64; ++tl) {
    float v = bp[(size_t)tl * EMB];
    float s = bs[(size_t)tl * EMB];
    mx = mx > v ? mx : v;
    sm += s;
  }
  pmaxo[e] = mx;
  psumo[e] = sm;
}

// ---------------- final linear: pooled[16,2048] @ W4 + b4 -> out[16,7] ----------------
__global__ __launch_bounds__(64) void final_kernel(const float* __restrict__ pmax, const float* __restrict__ psum,
    const float* __restrict__ W4, const float* __restrict__ b4, float* __restrict__ out) {
  int b = blockIdx.x, t = threadIdx.x;
  #pragma unroll
  for (int o = 0; o < OUT; ++o) {
    float acc = 0.f;
    for (int tt = t; tt < 2 * EMB; tt += 64) {
      float p = (tt < EMB) ? pmax[(size_t)b * EMB + tt]
                           : psum[(size_t)b * EMB + tt - EMB] * (1.0f / (float)NPT);
      acc += p * W4[(size_t)tt * OUT + o];
    }
    #pragma unroll
    for (int off = 32; off > 0; off >>= 1) acc += __shfl_down(acc, off);
    if (t == 0) out[b * OUT + o] = acc + b4[o];
  }
}

extern "C" void kernel_launch(void* const* d_in, const int* in_sizes, int n_in,
                              void* d_out, int out_size, void* d_ws, size_t ws_size,
                              hipStream_t stream) {
  const float* pos = (const float*)d_in[0];
  const float* W1 = (const float*)d_in[1];  const float* b1 = (const float*)d_in[2];
  const float* g1 = (const float*)d_in[3];  const float* be1 = (const float*)d_in[4];
  const float* W2 = (const float*)d_in[5];  const float* b2 = (const float*)d_in[6];
  const float* g2 = (const float*)d_in[7];  const float* be2 = (const float*)d_in[8];
  const float* W3 = (const float*)d_in[9];  const float* b3 = (const float*)d_in[10];
  const float* g3 = (const float*)d_in[11]; const float* be3 = (const float*)d_in[12];
  const float* W4 = (const float*)d_in[13]; const float* b4 = (const float*)d_in[14];
  float* out = (float*)d_out;

  // ---- workspace layout, total ~25.9 MiB (proven safe in rounds 4-8) ----
  char* ws = (char*)d_ws;
  unsigned short* idx = (unsigned short*)ws;               // NEDGE u16 = 1.25 MiB
  __half2* am = (__half2*)(ws + (size_t)NEDGE * 2);        // NNODE*C2 half2 = 16 MiB
  char* smallbase = (char*)(am + (size_t)NNODE * C2);

  double* dstats  = (double*)smallbase;           // 32 (27 used)
  double* G2      = dstats + 32;                  // 16384
  double* nodesum = G2 + 16384;                   // 128
  float* scale1 = (float*)(nodesum + 128);
  float* shift1 = scale1 + C1;
  float* scale2 = shift1 + C1;
  float* shift2 = scale2 + C2;
  float* scale3 = shift2 + C2;
  float* shift3 = scale3 + EMB;
  float* pooledmax = shift3 + EMB;                // 16*1024
  float* pooledsum = pooledmax + NB * EMB;        // 16*1024
  half2_t* w3h = (half2_t*)(pooledsum + NB * EMB);// 64*1024 half2 = 256 KiB
  char* scratch = (char*)(w3h + 64 * EMB);
  // lifetime-disjoint overlays on one ~8.45 MiB slab:
  float* eg_part   = (float*)scratch;             // 8192*256*4  = 8.00 MiB (edge2 -> finalize2)
  float* gram_part = (float*)scratch;             // 128*16512*4 = 8.06 MiB (gram_part -> gram_reduce)
  float* pp        = (float*)scratch;             // 1024*1024*4 = 4 MiB    (apply3pool -> poolreduce)
  float* psb       = pp + (size_t)1024 * EMB;     // 4 MiB

  hipMemsetAsync(dstats, 0, 32 * sizeof(double), stream);

  knn_kernel<<<NB * NPT / 4, 256, 0, stream>>>(pos, idx);
  packw3_kernel<<<64 * EMB / 256, 256, 0, stream>>>(W3, w3h);
  statse_kernel<<<512, 256, 0, stream>>>(pos, idx, dstats);
  finalize1_kernel<<<1, 64, 0, stream>>>(dstats, W1, b1, g1, be1, scale1, shift1);
  edge2_kernel<<<E2_BLOCKS, 256, 0, stream>>>(pos, idx, W1, b1, scale1, shift1, W2, b2, am, eg_part);
  finalize2_kernel<<<C2, 256, 0, stream>>>(eg_part, g2, be2, scale2, shift2);
  gram_part_kernel<<<GRAM_GRID, 256, 0, stream>>>(am, scale2, shift2, gram_part);
  gram_reduce_kernel<<<(GRAM_ELEMS + 255) / 256, 256, 0, stream>>>(gram_part, G2, nodesum);
  finalize3_kernel<<<EMB, 128, 0, stream>>>(G2, nodesum, W3, b3, g3, be3, scale3, shift3);
  apply3pool_kernel<<<dim3(1024, 2), 256, 0, stream>>>(am, scale2, shift2, w3h, b3, scale3, shift3, pp, psb);
  poolreduce_kernel<<<NB * EMB / 256, 256, 0, stream>>>(pp, psb, pooledmax, pooledsum);
  final_kernel<<<NB, 64, 0, stream>>>(pooledmax, pooledsum, W4, b4, out);
}